// Round 7
// baseline (218.649 us; speedup 1.0000x reference)
//
#include <hip/hip_runtime.h>
#include <hip/hip_bf16.h>
#include <stdint.h>

// GQA attention block, MI355X gfx950.
// R1-R4: attention ladder (swapped-QK^T, in-reg softmax, LDS-staged K/V, swizzle).
// R5: GEMMs 256x256/BK=64, counted vmcnt, swizzled LDS, XCD-chunked grid.
// R6: GEMMs -> true 8-phase schedule (4 phases/K-tile x 16 MFMA quadrants),
//     per-phase {ds_read || stage-issue -> bar -> lgkmcnt(0) -> MFMA -> bar},
//     vmcnt(4) once per K-tile (depth-2 prefetch, hazard-verified).

typedef __attribute__((ext_vector_type(4))) float f32x4;
typedef __attribute__((ext_vector_type(16))) float f32x16;
typedef __attribute__((ext_vector_type(8))) short sfrag;   // 8 bf16 bits
typedef __attribute__((ext_vector_type(8))) __bf16 bfrag;
typedef __attribute__((ext_vector_type(4))) unsigned int u32x4;
typedef unsigned short u16;

__device__ __forceinline__ f32x4 mfma16(sfrag a, sfrag b, f32x4 c) {
  return __builtin_amdgcn_mfma_f32_16x16x32_bf16(
      __builtin_bit_cast(bfrag, a), __builtin_bit_cast(bfrag, b), c, 0, 0, 0);
}
__device__ __forceinline__ f32x16 mfma32(sfrag a, sfrag b, f32x16 c) {
  return __builtin_amdgcn_mfma_f32_32x32x16_bf16(
      __builtin_bit_cast(bfrag, a), __builtin_bit_cast(bfrag, b), c, 0, 0, 0);
}
__device__ __forceinline__ u16 f2b(float f) {
  return __builtin_bit_cast(u16, (__bf16)f);
}
__device__ __forceinline__ unsigned pack2(float a, float b) {
  return (unsigned)f2b(a) | ((unsigned)f2b(b) << 16);
}
// a' = [a(0:31)|b(0:31)], b' = [a(32:63)|b(32:63)]
__device__ __forceinline__ void swap32(unsigned& a, unsigned& b) {
  asm("v_permlane32_swap_b32 %0, %1" : "+v"(a), "+v"(b));
}

#define GAS __attribute__((address_space(1)))
#define LAS __attribute__((address_space(3)))
__device__ __forceinline__ void gll16(const void* g, void* l) {
  __builtin_amdgcn_global_load_lds((GAS unsigned int*)g, (LAS unsigned int*)l, 16, 0, 0);
}

// ---------- f32 -> bf16 elementwise (x) ----------
__global__ __launch_bounds__(256) void k_convx(const float* __restrict__ X,
                                               u16* __restrict__ Y, int n) {
  int i = (blockIdx.x * 256 + threadIdx.x) * 4;
  if (i >= n) return;
  float4 v = *(const float4*)(X + i);
  *(ushort4*)(Y + i) = make_ushort4(f2b(v.x), f2b(v.y), f2b(v.z), f2b(v.w));
}

// ---------- W (2048 x N) f32 -> Wt (rowoff+N x 2048) bf16 transposed ----------
__global__ __launch_bounds__(256) void k_convT(const float* __restrict__ W,
                                               u16* __restrict__ Wt, int N, int rowoff) {
  __shared__ float tile[64][65];
  int n0 = blockIdx.x * 64, k0 = blockIdx.y * 64;
  #pragma unroll
  for (int p = 0; p < 16; ++p) {
    int idx = p * 256 + threadIdx.x;
    int kk = idx >> 6, nn = idx & 63;
    tile[kk][nn] = W[(size_t)(k0 + kk) * N + n0 + nn];
  }
  __syncthreads();
  #pragma unroll
  for (int p = 0; p < 16; ++p) {
    int idx = p * 256 + threadIdx.x;
    int nn = idx >> 6, kk = idx & 63;
    Wt[(size_t)(rowoff + n0 + nn) * 2048 + k0 + kk] = f2b(tile[kk][nn]);
  }
}

// ---------- GEMM 256x256/BK=64, 8 waves, 8-phase counted-vmcnt schedule ----------
// C(MxN f32) = A(MxK bf16) * Bt(NxK bf16)^T.  Grid 1D, XCD-chunked (nwg%8==0).
// LDS (128KB): buf(2) x { A: 2 halves x [128 rows][128B], B: same at +32768 }.
// Swizzle on both stage-source and frag-read: byte ^= ((row&7)<<4).
// Half-tile H (kind=H&3: 0 A-h0, 1 B-h0, 2 A-h1, 3 B-h1; tile=H>>2), 2 gll16 each.
// Phase P of tile t stages H=4t+6+P; vmcnt(4) at end of ph3 (tile t+1 landed,
// tile t+2's first 2 halves in flight). Reads: ph0 A-lo+B-lo(12), ph1 A-hi(8),
// ph2 B-hi(4), ph3 none (held) -> every region's last read precedes its
// overwriting stage issue by >= 1 end-barrier (race-free at depth 2).
__global__ __launch_bounds__(512, 1) void k_gemm8(const u16* __restrict__ A,
                                                  const u16* __restrict__ Bt,
                                                  float* __restrict__ C,
                                                  int N, int K, int GY) {
  __shared__ u16 lds[2][32768];                 // 128 KB
  char* const L = (char*)&lds[0][0];
  const int tid = threadIdx.x;
  const int q8 = gridDim.x >> 3;
  const int id2 = (blockIdx.x & 7) * q8 + (blockIdx.x >> 3);
  const int by = id2 % GY, bx = id2 / GY;
  const int wid = tid >> 6, lane = tid & 63;
  const int wm = wid >> 2, wn = wid & 3;        // 2 x 4 waves, 128x64 C each
  const int l16 = lane & 15, l4 = lane >> 4;
  const size_t K2 = (size_t)K * 2;
  const char* Ab = (const char*)(A + (size_t)(by * 256) * K);
  const char* Bb = (const char*)(Bt + (size_t)(bx * 256) * K);
  const int NT = K >> 6;

  auto stage = [&](int H) {
    const int T = H >> 2;
    if (T >= NT) return;
    const int kind = H & 3;
    const char* gb = (kind & 1) ? Bb : Ab;
    const int h = kind >> 1;
    char* ldst = L + ((T & 1) * 65536) + ((kind & 1) * 32768) + h * 16384;
    #pragma unroll
    for (int ld = 0; ld < 2; ++ld) {
      const int p = ld * 8192 + tid * 16;
      const int r = p >> 7;
      const int cb = (p & 127) ^ ((r & 7) << 4);
      gll16(gb + (size_t)(h * 128 + r) * K2 + (size_t)T * 128 + cb, ldst + p);
    }
  };

  // per-thread read offsets (byte, within buf)
  const int swz = (l16 & 7) << 4;
  const int c0 = (l4 * 16) ^ swz;               // ks=0
  const int c1 = (64 + l4 * 16) ^ swz;          // ks=1
  const int aOff = wm * 16384 + l16 * 128;                          // + m*2048
  const int bOff = 32768 + (wn >> 1) * 16384 + ((wn & 1) * 64 + l16) * 128; // + n*2048

  f32x4 acc[8][4];
  #pragma unroll
  for (int m = 0; m < 8; ++m)
    #pragma unroll
    for (int n = 0; n < 4; ++n) acc[m][n] = f32x4{0.f, 0.f, 0.f, 0.f};

  // prologue: tile0 full (H0..H3) + tile1 first two halves (H4,H5)
  stage(0); stage(1); stage(2); stage(3); stage(4); stage(5);
  asm volatile("s_waitcnt vmcnt(4)" ::: "memory");   // tile0 landed
  __builtin_amdgcn_s_barrier();

  sfrag aLo[4][2], aHi[4][2], bLo[2][2], bHi[2][2];
  for (int t = 0; t < NT; ++t) {
    const char* bp = L + ((t & 1) << 16);
    // ---- phase 0: read A-lo + B-lo, stage H=4t+6, MFMA q(mlo,nlo) ----
    #pragma unroll
    for (int m = 0; m < 4; ++m) {
      aLo[m][0] = *(const sfrag*)(bp + aOff + m * 2048 + c0);
      aLo[m][1] = *(const sfrag*)(bp + aOff + m * 2048 + c1);
    }
    #pragma unroll
    for (int n = 0; n < 2; ++n) {
      bLo[n][0] = *(const sfrag*)(bp + bOff + n * 2048 + c0);
      bLo[n][1] = *(const sfrag*)(bp + bOff + n * 2048 + c1);
    }
    stage(4 * t + 6);
    __builtin_amdgcn_s_barrier();
    asm volatile("s_waitcnt lgkmcnt(0)" ::: "memory");
    __builtin_amdgcn_s_setprio(1);
    #pragma unroll
    for (int m = 0; m < 4; ++m)
      #pragma unroll
      for (int n = 0; n < 2; ++n) {
        acc[m][n] = mfma16(aLo[m][0], bLo[n][0], acc[m][n]);
        acc[m][n] = mfma16(aLo[m][1], bLo[n][1], acc[m][n]);
      }
    __builtin_amdgcn_s_setprio(0);
    __builtin_amdgcn_s_barrier();
    // ---- phase 1: read A-hi, stage H=4t+7, MFMA q(mhi,nlo) ----
    #pragma unroll
    for (int m = 0; m < 4; ++m) {
      aHi[m][0] = *(const sfrag*)(bp + aOff + (m + 4) * 2048 + c0);
      aHi[m][1] = *(const sfrag*)(bp + aOff + (m + 4) * 2048 + c1);
    }
    stage(4 * t + 7);
    __builtin_amdgcn_s_barrier();
    asm volatile("s_waitcnt lgkmcnt(0)" ::: "memory");
    __builtin_amdgcn_s_setprio(1);
    #pragma unroll
    for (int m = 0; m < 4; ++m)
      #pragma unroll
      for (int n = 0; n < 2; ++n) {
        acc[m + 4][n] = mfma16(aHi[m][0], bLo[n][0], acc[m + 4][n]);
        acc[m + 4][n] = mfma16(aHi[m][1], bLo[n][1], acc[m + 4][n]);
      }
    __builtin_amdgcn_s_setprio(0);
    __builtin_amdgcn_s_barrier();
    // ---- phase 2: read B-hi, stage H=4t+8, MFMA q(mhi,nhi) ----
    #pragma unroll
    for (int n = 0; n < 2; ++n) {
      bHi[n][0] = *(const sfrag*)(bp + bOff + (n + 2) * 2048 + c0);
      bHi[n][1] = *(const sfrag*)(bp + bOff + (n + 2) * 2048 + c1);
    }
    stage(4 * t + 8);
    __builtin_amdgcn_s_barrier();
    asm volatile("s_waitcnt lgkmcnt(0)" ::: "memory");
    __builtin_amdgcn_s_setprio(1);
    #pragma unroll
    for (int m = 0; m < 4; ++m)
      #pragma unroll
      for (int n = 0; n < 2; ++n) {
        acc[m + 4][n + 2] = mfma16(aHi[m][0], bHi[n][0], acc[m + 4][n + 2]);
        acc[m + 4][n + 2] = mfma16(aHi[m][1], bHi[n][1], acc[m + 4][n + 2]);
      }
    __builtin_amdgcn_s_setprio(0);
    __builtin_amdgcn_s_barrier();
    // ---- phase 3: no reads (aLo,bHi held), stage H=4t+9, MFMA q(mlo,nhi) ----
    stage(4 * t + 9);
    __builtin_amdgcn_s_barrier();
    __builtin_amdgcn_s_setprio(1);
    #pragma unroll
    for (int m = 0; m < 4; ++m)
      #pragma unroll
      for (int n = 0; n < 2; ++n) {
        acc[m][n + 2] = mfma16(aLo[m][0], bHi[n][0], acc[m][n + 2]);
        acc[m][n + 2] = mfma16(aLo[m][1], bHi[n][1], acc[m][n + 2]);
      }
    __builtin_amdgcn_s_setprio(0);
    if (t + 2 < NT)      asm volatile("s_waitcnt vmcnt(4)" ::: "memory");
    else if (t + 1 < NT) asm volatile("s_waitcnt vmcnt(0)" ::: "memory");
    __builtin_amdgcn_s_barrier();
  }

  float* Cb = C + (size_t)(by * 256 + wm * 128) * N + bx * 256 + wn * 64;
  #pragma unroll
  for (int m = 0; m < 8; ++m)
    #pragma unroll
    for (int n = 0; n < 4; ++n)
      #pragma unroll
      for (int r = 0; r < 4; ++r)
        Cb[(size_t)(m * 16 + l4 * 4 + r) * N + n * 16 + l16] = acc[m][n][r];
}

// ---------- RoPE + layout ----------
__global__ __launch_bounds__(256) void k_rope(const float* __restrict__ QKV,
                                              const int* __restrict__ sp,
                                              u16* __restrict__ Qb, u16* __restrict__ Kb,
                                              float* __restrict__ Kout,
                                              float* __restrict__ Vout) {
  const int row = blockIdx.x;          // b*2048 + t
  const int b = row >> 11, t = row & 2047;
  __shared__ float cs[32], sn[32];
  if (threadIdx.x < 32) {
    int j = threadIdx.x;
    float freq = powf(10000.0f, -(float)j * (1.0f / 32.0f));
    float ang = (float)(sp[0] + t) * freq;
    cs[j] = cosf(ang);
    sn[j] = sinf(ang);
  }
  __syncthreads();
  const float QSCALE = 0.125f * 1.44269504f;   // 1/sqrt(hd) * log2(e)
  const float* src = QKV + (size_t)row * 3072;
  for (int p = threadIdx.x; p < 1280; p += 256) {
    int head = p >> 5, j = p & 31;
    float c = cs[j], s = sn[j];
    float x1 = src[head * 64 + j], x2 = src[head * 64 + j + 32];
    float o1 = x1 * c - x2 * s, o2 = x1 * s + x2 * c;
    if (head < 32) {
      size_t o = ((size_t)(b * 32 + head) * 2048 + t) * 64 + j;
      Qb[o] = f2b(o1 * QSCALE);
      Qb[o + 32] = f2b(o2 * QSCALE);
    } else {
      int g = head - 32;
      size_t o = ((size_t)(b * 8 + g) * 2048 + t) * 64 + j;
      Kb[o] = f2b(o1);  Kb[o + 32] = f2b(o2);
      Kout[o] = o1;     Kout[o + 32] = o2;
    }
  }
  for (int p = threadIdx.x; p < 512; p += 256) {
    int g = p >> 6, d = p & 63;
    Vout[((size_t)(b * 8 + g) * 2048 + t) * 64 + d] = src[2560 + g * 64 + d];
  }
}

// ---------- V transpose: QKV cols 2560..3071 -> Vt bf16 (B,G,hd,T) ----------
__global__ __launch_bounds__(256) void k_vtrans(const float* __restrict__ QKV,
                                                u16* __restrict__ Vt) {
  __shared__ float tile[64][65];
  int t0 = blockIdx.x * 64;
  int bg = blockIdx.y, b = bg >> 3, g = bg & 7;
  #pragma unroll
  for (int p = 0; p < 16; ++p) {
    int idx = p * 256 + threadIdx.x;
    int tt = idx >> 6, d = idx & 63;
    tile[tt][d] = QKV[((size_t)(b * 2048 + t0 + tt)) * 3072 + 2560 + g * 64 + d];
  }
  __syncthreads();
  #pragma unroll
  for (int p = 0; p < 16; ++p) {
    int idx = p * 256 + threadIdx.x;
    int d = idx >> 6, tt = idx & 63;
    Vt[((size_t)(b * 8 + g) * 64 + d) * 2048 + t0 + tt] = f2b(tile[tt][d]);
  }
}

// ---------- Flash attention v5: LDS-staged K/V, swizzled, 4 head-waves share ----------
__device__ __forceinline__ void pv4(const float* p, sfrag v0a, sfrag v0b,
                                    sfrag v1a, sfrag v1b,
                                    f32x16& O0, f32x16& O1, float& l) {
  unsigned w[8];
  #pragma unroll
  for (int j = 0; j < 8; ++j) w[j] = pack2(p[2 * j], p[2 * j + 1]);
  swap32(w[0], w[2]);
  swap32(w[1], w[3]);
  swap32(w[4], w[6]);
  swap32(w[5], w[7]);
  const sfrag pf0 = __builtin_bit_cast(sfrag, u32x4{w[0], w[1], w[2], w[3]});
  const sfrag pf1 = __builtin_bit_cast(sfrag, u32x4{w[4], w[5], w[6], w[7]});
  O0 = mfma32(v0a, pf0, O0);
  O0 = mfma32(v0b, pf1, O0);
  O1 = mfma32(v1a, pf0, O1);
  O1 = mfma32(v1b, pf1, O1);
  float s[8];
  #pragma unroll
  for (int j = 0; j < 8; ++j) s[j] = p[j] + p[j + 8];
  #pragma unroll
  for (int j = 0; j < 4; ++j) s[j] = s[j] + s[j + 4];
  l += (s[0] + s[1]) + (s[2] + s[3]);
}

__device__ __forceinline__ void tile64_l(const u16* __restrict__ buf,
                                         const sfrag* qf, int hi, int l31, int swz,
                                         f32x16& O0, f32x16& O1, float& l) {
  const char* Kl = (const char*)buf;
  const char* Vl = Kl + 8192;
  const int rb = l31 * 128;
  f32x16 Sa = {}, Sb = {};
  #pragma unroll
  for (int ks = 0; ks < 4; ++ks) {
    const int col = (hi * 16 + ks * 32) ^ swz;
    const sfrag ka = *(const sfrag*)(Kl + rb + col);
    const sfrag kb = *(const sfrag*)(Kl + rb + col + 4096);
    Sa = mfma32(ka, qf[ks], Sa);
    Sb = mfma32(kb, qf[ks], Sb);
  }
  float pa[16], pb[16];
  #pragma unroll
  for (int r = 0; r < 16; ++r) {
    pa[r] = __builtin_amdgcn_exp2f(Sa[r]);
    pb[r] = __builtin_amdgcn_exp2f(Sb[r]);
  }
  sfrag v0[4], v1[4];
  #pragma unroll
  for (int s = 0; s < 4; ++s) {
    const int col = (s * 32 + hi * 16) ^ swz;
    v0[s] = *(const sfrag*)(Vl + rb + col);
    v1[s] = *(const sfrag*)(Vl + rb + col + 4096);
  }
  pv4(pa, v0[0], v0[1], v1[0], v1[1], O0, O1, l);
  pv4(pb, v0[2], v0[3], v1[2], v1[3], O0, O1, l);
}

template<bool MASKED>
__device__ __forceinline__ void tile32_l(const u16* __restrict__ buf, int c,
                                         const sfrag* qf, int hi, int l31, int swz,
                                         f32x16& O0, f32x16& O1, float& l) {
  const char* Kl = (const char*)buf;
  const char* Vl = Kl + 8192;
  const int rb = l31 * 128;
  f32x16 S = {};
  #pragma unroll
  for (int ks = 0; ks < 4; ++ks) {
    const int col = (hi * 16 + ks * 32) ^ swz;
    const sfrag k = *(const sfrag*)(Kl + c * 4096 + rb + col);
    S = mfma32(k, qf[ks], S);
  }
  float p[16];
  #pragma unroll
  for (int r = 0; r < 16; ++r) {
    float s = S[r];
    if (MASKED) {
      int kvo = (r & 3) + 8 * (r >> 2) + 4 * hi;
      if (kvo > l31) s = -__builtin_inff();
    }
    p[r] = __builtin_amdgcn_exp2f(s);
  }
  const int colA = (c * 64 + hi * 16) ^ swz;
  const int colB = (c * 64 + 32 + hi * 16) ^ swz;
  const sfrag v0a = *(const sfrag*)(Vl + rb + colA);
  const sfrag v0b = *(const sfrag*)(Vl + rb + colB);
  const sfrag v1a = *(const sfrag*)(Vl + rb + colA + 4096);
  const sfrag v1b = *(const sfrag*)(Vl + rb + colB + 4096);
  pv4(p, v0a, v0b, v1a, v1b, O0, O1, l);
}

__global__ __launch_bounds__(256, 4) void k_attn5(const u16* __restrict__ Qb,
                                                  const u16* __restrict__ Kb,
                                                  const u16* __restrict__ Vt,
                                                  u16* __restrict__ attOut) {
  __shared__ u16 lds[2][8192];
  const int bid = blockIdx.x;
  const int qb = 63 - (bid >> 4);
  const int bg = bid & 15;
  const int b = bg >> 3, g = bg & 7;
  const int wave = threadIdx.x >> 6, lane = threadIdx.x & 63;
  const int h = g * 4 + wave;
  const int hi = lane >> 5, l31 = lane & 31;
  const int qrow0 = qb * 32;
  const int swz = (l31 & 7) << 4;

  const u16* Qp = Qb + (((size_t)b * 32 + h) * 2048 + qrow0 + l31) * 64 + hi * 8;
  sfrag qf[4];
  #pragma unroll
  for (int ks = 0; ks < 4; ++ks) qf[ks] = *(const sfrag*)(Qp + ks * 16);

  const char* Kg = (const char*)(Kb + ((size_t)b * 8 + g) * (2048 * 64));
  const char* Vg = (const char*)(Vt + ((size_t)b * 8 + g) * (64 * 2048));

  auto stage = [&](int bufi, int t) {
    const char* Ktile = Kg + (size_t)t * 8192;
    const char* Vtile = Vg + t * 128;
    #pragma unroll
    for (int rd = 0; rd < 2; ++rd) {
      const int p = rd * 4096 + threadIdx.x * 16;
      const int d = p >> 7;
      const int cb = (p & 127) ^ ((d & 7) << 4);
      const int lbase = rd * 4096 + wave * 1024;
      gll16(Ktile + d * 128 + cb, (char*)&lds[bufi][0] + lbase);
      gll16(Vtile + (size_t)d * 4096 + cb, (char*)&lds[bufi][0] + 8192 + lbase);
    }
  };

  f32x16 O0 = {}, O1 = {};
  float lsum = 0.f;
  const int nfull = qrow0 >> 6;
  int cur = 0;
  stage(0, 0);
  for (int t = 0; t < nfull; ++t) {
    __syncthreads();
    stage(cur ^ 1, t + 1);
    tile64_l(lds[cur], qf, hi, l31, swz, O0, O1, lsum);
    cur ^= 1;
  }
  __syncthreads();
  if (qb & 1) {
    tile32_l<false>(lds[cur], 0, qf, hi, l31, swz, O0, O1, lsum);
    tile32_l<true>(lds[cur], 1, qf, hi, l31, swz, O0, O1, lsum);
  } else {
    tile32_l<true>(lds[cur], 0, qf, hi, l31, swz, O0, O1, lsum);
  }

  const float ltot = lsum + __shfl_xor(lsum, 32);
  const float inv = 1.0f / ltot;
  const size_t orow = ((size_t)b * 2048 + qrow0 + l31) * 2048 + h * 64;
  #pragma unroll
  for (int dt = 0; dt < 2; ++dt) {
    const f32x16& O = dt ? O1 : O0;
    #pragma unroll
    for (int k = 0; k < 4; ++k) {
      ushort4 o;
      o.x = f2b(O[4 * k + 0] * inv);
      o.y = f2b(O[4 * k + 1] * inv);
      o.z = f2b(O[4 * k + 2] * inv);
      o.w = f2b(O[4 * k + 3] * inv);
      *(ushort4*)&attOut[orow + dt * 32 + 8 * k + 4 * hi] = o;
    }
  }
}

extern "C" void kernel_launch(void* const* d_in, const int* in_sizes, int n_in,
                              void* d_out, int out_size, void* d_ws, size_t ws_size,
                              hipStream_t stream) {
  const float* x  = (const float*)d_in[0];
  const float* Wq = (const float*)d_in[1];
  const float* Wk = (const float*)d_in[2];
  const float* Wv = (const float*)d_in[3];
  const float* Wo = (const float*)d_in[4];
  const int* sp   = (const int*)d_in[5];
  float* y    = (float*)d_out;            // (B,T,2048) f32
  float* Kout = y + 8388608;              // (B,G,T,64) f32
  float* Vout = y + 10485760;             // (B,G,T,64) f32

  char* ws = (char*)d_ws;
  u16*   xb     = (u16*)(ws + 0);          // 16 MiB (reused as attOut later)
  u16*   Wqkvt  = (u16*)(ws + 16777216);   // 12 MiB  (3072 x 2048 bf16, transposed)
  u16*   Wot    = (u16*)(ws + 29360128);   // 8 MiB
  float* QKV    = (float*)(ws + 37748736); // 48 MiB  (4096 x 3072 f32)
  u16*   Qbuf   = (u16*)(ws + 88080384);   // 16 MiB  (B,H,T,hd) bf16, pre-scaled
  u16*   Kbuf   = (u16*)(ws + 104857600);  // 4 MiB   (B,G,T,hd) bf16
  u16*   Vt     = (u16*)(ws + 109051904);  // 4 MiB   (B,G,hd,T) bf16
  u16*   attOut = xb;                      // alias: xb dead after QKV GEMM

  k_convx<<<8192, 256, 0, stream>>>(x, xb, 8388608);
  k_convT<<<dim3(32, 32), 256, 0, stream>>>(Wq, Wqkvt, 2048, 0);
  k_convT<<<dim3(8, 32), 256, 0, stream>>>(Wk, Wqkvt, 512, 2048);
  k_convT<<<dim3(8, 32), 256, 0, stream>>>(Wv, Wqkvt, 512, 2560);
  k_convT<<<dim3(32, 32), 256, 0, stream>>>(Wo, Wot, 2048, 0);
  k_gemm8<<<192, 512, 0, stream>>>(xb, Wqkvt, QKV, 3072, 2048, 16);
  k_rope<<<4096, 256, 0, stream>>>(QKV, sp, Qbuf, Kbuf, Kout, Vout);
  k_vtrans<<<dim3(32, 16), 256, 0, stream>>>(QKV, Vt);
  k_attn5<<<1024, 256, 0, stream>>>(Qbuf, Kbuf, Vt, attOut);
  k_gemm8<<<128, 512, 0, stream>>>(attOut, Wot, y, 2048, 2048, 16);
}

// Round 8
// 213.370 us; speedup vs baseline: 1.0247x; 1.0247x over previous
//
#include <hip/hip_runtime.h>
#include <hip/hip_bf16.h>
#include <stdint.h>

// GQA attention block, MI355X gfx950.
// R1-R4: attention ladder (swapped-QK^T, in-reg softmax, LDS-staged K/V, swizzle).
// R5-R6: GEMMs 256x256/BK=64 8-phase counted-vmcnt, swizzled LDS, XCD-chunked grid.
// R7: RoPE + output layout fused into QKV-GEMM epilogue (each wave's 64 cols = one
//     head; pair (j,j+32) = acc[m][n]/acc[m][n+2]); cos/sin table kernel; QKV f32
//     intermediate + k_rope eliminated; vtrans reads Vout; convT x3 merged.

typedef __attribute__((ext_vector_type(4))) float f32x4;
typedef __attribute__((ext_vector_type(16))) float f32x16;
typedef __attribute__((ext_vector_type(8))) short sfrag;   // 8 bf16 bits
typedef __attribute__((ext_vector_type(8))) __bf16 bfrag;
typedef __attribute__((ext_vector_type(4))) unsigned int u32x4;
typedef unsigned short u16;

__device__ __forceinline__ f32x4 mfma16(sfrag a, sfrag b, f32x4 c) {
  return __builtin_amdgcn_mfma_f32_16x16x32_bf16(
      __builtin_bit_cast(bfrag, a), __builtin_bit_cast(bfrag, b), c, 0, 0, 0);
}
__device__ __forceinline__ f32x16 mfma32(sfrag a, sfrag b, f32x16 c) {
  return __builtin_amdgcn_mfma_f32_32x32x16_bf16(
      __builtin_bit_cast(bfrag, a), __builtin_bit_cast(bfrag, b), c, 0, 0, 0);
}
__device__ __forceinline__ u16 f2b(float f) {
  return __builtin_bit_cast(u16, (__bf16)f);
}
__device__ __forceinline__ unsigned pack2(float a, float b) {
  return (unsigned)f2b(a) | ((unsigned)f2b(b) << 16);
}
// a' = [a(0:31)|b(0:31)], b' = [a(32:63)|b(32:63)]
__device__ __forceinline__ void swap32(unsigned& a, unsigned& b) {
  asm("v_permlane32_swap_b32 %0, %1" : "+v"(a), "+v"(b));
}

#define GAS __attribute__((address_space(1)))
#define LAS __attribute__((address_space(3)))
__device__ __forceinline__ void gll16(const void* g, void* l) {
  __builtin_amdgcn_global_load_lds((GAS unsigned int*)g, (LAS unsigned int*)l, 16, 0, 0);
}

// ---------- f32 -> bf16 elementwise (x) ----------
__global__ __launch_bounds__(256) void k_convx(const float* __restrict__ X,
                                               u16* __restrict__ Y, int n) {
  int i = (blockIdx.x * 256 + threadIdx.x) * 4;
  if (i >= n) return;
  float4 v = *(const float4*)(X + i);
  *(ushort4*)(Y + i) = make_ushort4(f2b(v.x), f2b(v.y), f2b(v.z), f2b(v.w));
}

// ---------- cos/sin table: csn[t][j] = {cos,sin}((sp+t) * 10000^(-j/32)) ----------
__global__ __launch_bounds__(256) void k_csn(const int* __restrict__ sp,
                                             float2* __restrict__ csn) {
  const int i = blockIdx.x * 256 + threadIdx.x;   // 65536 = 2048 x 32
  const int t = i >> 5, j = i & 31;
  const float freq = powf(10000.0f, -(float)j * (1.0f / 32.0f));
  const float ang = (float)(sp[0] + t) * freq;
  csn[i] = make_float2(cosf(ang), sinf(ang));
}

// ---------- Wq|Wk|Wv (2048 x N) f32 -> Wt (3072 x 2048) bf16 transposed ----------
__global__ __launch_bounds__(256) void k_convT3(const float* __restrict__ Wq,
                                                const float* __restrict__ Wk,
                                                const float* __restrict__ Wv,
                                                u16* __restrict__ Wt) {
  __shared__ float tile[64][65];
  const int n0g = blockIdx.x * 64;   // 0..3071 (global output row)
  const float* W; int N, n0;
  if (n0g < 2048)      { W = Wq; N = 2048; n0 = n0g; }
  else if (n0g < 2560) { W = Wk; N = 512;  n0 = n0g - 2048; }
  else                 { W = Wv; N = 512;  n0 = n0g - 2560; }
  const int k0 = blockIdx.y * 64;
  #pragma unroll
  for (int p = 0; p < 16; ++p) {
    int idx = p * 256 + threadIdx.x;
    int kk = idx >> 6, nn = idx & 63;
    tile[kk][nn] = W[(size_t)(k0 + kk) * N + n0 + nn];
  }
  __syncthreads();
  #pragma unroll
  for (int p = 0; p < 16; ++p) {
    int idx = p * 256 + threadIdx.x;
    int nn = idx >> 6, kk = idx & 63;
    Wt[(size_t)(n0g + nn) * 2048 + k0 + kk] = f2b(tile[kk][nn]);
  }
}

// ---------- Wo (2048 x 2048) f32 -> Wot bf16 transposed ----------
__global__ __launch_bounds__(256) void k_convT(const float* __restrict__ W,
                                               u16* __restrict__ Wt, int N) {
  __shared__ float tile[64][65];
  int n0 = blockIdx.x * 64, k0 = blockIdx.y * 64;
  #pragma unroll
  for (int p = 0; p < 16; ++p) {
    int idx = p * 256 + threadIdx.x;
    int kk = idx >> 6, nn = idx & 63;
    tile[kk][nn] = W[(size_t)(k0 + kk) * N + n0 + nn];
  }
  __syncthreads();
  #pragma unroll
  for (int p = 0; p < 16; ++p) {
    int idx = p * 256 + threadIdx.x;
    int nn = idx >> 6, kk = idx & 63;
    Wt[(size_t)(n0 + nn) * 2048 + k0 + kk] = f2b(tile[kk][nn]);
  }
}

// ---------- GEMM 256x256/BK=64, 8 waves, 8-phase counted-vmcnt schedule ----------
// MODE 0: plain C f32 write (out-proj).  MODE 1: QKV fused epilogue -> RoPE +
// Qb bf16 (pre-scaled) / Kb bf16 + Kout f32 / Vout f32.  Core loop identical.
template<int MODE>
__global__ __launch_bounds__(512, 1) void k_gemm8(const u16* __restrict__ A,
                                                  const u16* __restrict__ Bt,
                                                  float* __restrict__ C,
                                                  int N, int K, int GY,
                                                  const float2* __restrict__ csn,
                                                  u16* __restrict__ Qb,
                                                  u16* __restrict__ Kb,
                                                  float* __restrict__ Kout,
                                                  float* __restrict__ Vout) {
  __shared__ u16 lds[2][32768];                 // 128 KB
  char* const L = (char*)&lds[0][0];
  const int tid = threadIdx.x;
  const int q8 = gridDim.x >> 3;
  const int id2 = (blockIdx.x & 7) * q8 + (blockIdx.x >> 3);
  const int by = id2 % GY, bx = id2 / GY;
  const int wid = tid >> 6, lane = tid & 63;
  const int wm = wid >> 2, wn = wid & 3;        // 2 x 4 waves, 128x64 C each
  const int l16 = lane & 15, l4 = lane >> 4;
  const size_t K2 = (size_t)K * 2;
  const char* Ab = (const char*)(A + (size_t)(by * 256) * K);
  const char* Bb = (const char*)(Bt + (size_t)(bx * 256) * K);
  const int NT = K >> 6;

  auto stage = [&](int H) {
    const int T = H >> 2;
    if (T >= NT) return;
    const int kind = H & 3;
    const char* gb = (kind & 1) ? Bb : Ab;
    const int h = kind >> 1;
    char* ldst = L + ((T & 1) * 65536) + ((kind & 1) * 32768) + h * 16384;
    #pragma unroll
    for (int ld = 0; ld < 2; ++ld) {
      const int p = ld * 8192 + tid * 16;
      const int r = p >> 7;
      const int cb = (p & 127) ^ ((r & 7) << 4);
      gll16(gb + (size_t)(h * 128 + r) * K2 + (size_t)T * 128 + cb, ldst + p);
    }
  };

  const int swz = (l16 & 7) << 4;
  const int c0 = (l4 * 16) ^ swz;               // ks=0
  const int c1 = (64 + l4 * 16) ^ swz;          // ks=1
  const int aOff = wm * 16384 + l16 * 128;
  const int bOff = 32768 + (wn >> 1) * 16384 + ((wn & 1) * 64 + l16) * 128;

  f32x4 acc[8][4];
  #pragma unroll
  for (int m = 0; m < 8; ++m)
    #pragma unroll
    for (int n = 0; n < 4; ++n) acc[m][n] = f32x4{0.f, 0.f, 0.f, 0.f};

  stage(0); stage(1); stage(2); stage(3); stage(4); stage(5);
  asm volatile("s_waitcnt vmcnt(4)" ::: "memory");
  __builtin_amdgcn_s_barrier();

  sfrag aLo[4][2], aHi[4][2], bLo[2][2], bHi[2][2];
  for (int t = 0; t < NT; ++t) {
    const char* bp = L + ((t & 1) << 16);
    // ---- phase 0: read A-lo + B-lo, MFMA q(mlo,nlo) ----
    #pragma unroll
    for (int m = 0; m < 4; ++m) {
      aLo[m][0] = *(const sfrag*)(bp + aOff + m * 2048 + c0);
      aLo[m][1] = *(const sfrag*)(bp + aOff + m * 2048 + c1);
    }
    #pragma unroll
    for (int n = 0; n < 2; ++n) {
      bLo[n][0] = *(const sfrag*)(bp + bOff + n * 2048 + c0);
      bLo[n][1] = *(const sfrag*)(bp + bOff + n * 2048 + c1);
    }
    stage(4 * t + 6);
    __builtin_amdgcn_s_barrier();
    asm volatile("s_waitcnt lgkmcnt(0)" ::: "memory");
    __builtin_amdgcn_s_setprio(1);
    #pragma unroll
    for (int m = 0; m < 4; ++m)
      #pragma unroll
      for (int n = 0; n < 2; ++n) {
        acc[m][n] = mfma16(aLo[m][0], bLo[n][0], acc[m][n]);
        acc[m][n] = mfma16(aLo[m][1], bLo[n][1], acc[m][n]);
      }
    __builtin_amdgcn_s_setprio(0);
    __builtin_amdgcn_s_barrier();
    // ---- phase 1: read A-hi, MFMA q(mhi,nlo) ----
    #pragma unroll
    for (int m = 0; m < 4; ++m) {
      aHi[m][0] = *(const sfrag*)(bp + aOff + (m + 4) * 2048 + c0);
      aHi[m][1] = *(const sfrag*)(bp + aOff + (m + 4) * 2048 + c1);
    }
    stage(4 * t + 7);
    __builtin_amdgcn_s_barrier();
    asm volatile("s_waitcnt lgkmcnt(0)" ::: "memory");
    __builtin_amdgcn_s_setprio(1);
    #pragma unroll
    for (int m = 0; m < 4; ++m)
      #pragma unroll
      for (int n = 0; n < 2; ++n) {
        acc[m + 4][n] = mfma16(aHi[m][0], bLo[n][0], acc[m + 4][n]);
        acc[m + 4][n] = mfma16(aHi[m][1], bLo[n][1], acc[m + 4][n]);
      }
    __builtin_amdgcn_s_setprio(0);
    __builtin_amdgcn_s_barrier();
    // ---- phase 2: read B-hi, MFMA q(mhi,nhi) ----
    #pragma unroll
    for (int n = 0; n < 2; ++n) {
      bHi[n][0] = *(const sfrag*)(bp + bOff + (n + 2) * 2048 + c0);
      bHi[n][1] = *(const sfrag*)(bp + bOff + (n + 2) * 2048 + c1);
    }
    stage(4 * t + 8);
    __builtin_amdgcn_s_barrier();
    asm volatile("s_waitcnt lgkmcnt(0)" ::: "memory");
    __builtin_amdgcn_s_setprio(1);
    #pragma unroll
    for (int m = 0; m < 4; ++m)
      #pragma unroll
      for (int n = 0; n < 2; ++n) {
        acc[m + 4][n + 2] = mfma16(aHi[m][0], bHi[n][0], acc[m + 4][n + 2]);
        acc[m + 4][n + 2] = mfma16(aHi[m][1], bHi[n][1], acc[m + 4][n + 2]);
      }
    __builtin_amdgcn_s_setprio(0);
    __builtin_amdgcn_s_barrier();
    // ---- phase 3: no reads (aLo,bHi held), MFMA q(mlo,nhi) ----
    stage(4 * t + 9);
    __builtin_amdgcn_s_barrier();
    __builtin_amdgcn_s_setprio(1);
    #pragma unroll
    for (int m = 0; m < 4; ++m)
      #pragma unroll
      for (int n = 0; n < 2; ++n) {
        acc[m][n + 2] = mfma16(aLo[m][0], bHi[n][0], acc[m][n + 2]);
        acc[m][n + 2] = mfma16(aLo[m][1], bHi[n][1], acc[m][n + 2]);
      }
    __builtin_amdgcn_s_setprio(0);
    if (t + 2 < NT)      asm volatile("s_waitcnt vmcnt(4)" ::: "memory");
    else if (t + 1 < NT) asm volatile("s_waitcnt vmcnt(0)" ::: "memory");
    __builtin_amdgcn_s_barrier();
  }

  if constexpr (MODE == 0) {
    float* Cb = C + (size_t)(by * 256 + wm * 128) * N + bx * 256 + wn * 64;
    #pragma unroll
    for (int m = 0; m < 8; ++m)
      #pragma unroll
      for (int n = 0; n < 4; ++n)
        #pragma unroll
        for (int r = 0; r < 4; ++r)
          Cb[(size_t)(m * 16 + l4 * 4 + r) * N + n * 16 + l16] = acc[m][n][r];
  } else {
    // Fused RoPE + layout. This wave's 64 cols = head (bx*4+wn).
    const int head = bx * 4 + wn;
    const int row0 = by * 256 + wm * 128;
    if (head < 40) {                    // Q (0..31) or K (32..39): rope
      const float QS = 0.125f * 1.44269504f;   // 1/sqrt(hd) * log2(e)
      #pragma unroll
      for (int m = 0; m < 8; ++m)
        #pragma unroll
        for (int r = 0; r < 4; ++r) {
          const int tg = row0 + m * 16 + l4 * 4 + r;
          const int b = tg >> 11, t = tg & 2047;
          #pragma unroll
          for (int n = 0; n < 2; ++n) {
            const int j = n * 16 + l16;
            const float2 cz = csn[t * 32 + j];
            const float x1 = acc[m][n][r], x2 = acc[m][n + 2][r];
            const float o1 = x1 * cz.x - x2 * cz.y;
            const float o2 = x1 * cz.y + x2 * cz.x;
            if (head < 32) {
              const size_t o = (((size_t)b * 32 + head) * 2048 + t) * 64 + j;
              Qb[o] = f2b(o1 * QS);
              Qb[o + 32] = f2b(o2 * QS);
            } else {
              const int g = head - 32;
              const size_t o = (((size_t)b * 8 + g) * 2048 + t) * 64 + j;
              Kb[o] = f2b(o1);  Kb[o + 32] = f2b(o2);
              Kout[o] = o1;     Kout[o + 32] = o2;
            }
          }
        }
    } else {                            // V (40..47): plain copy-out f32
      const int g = head - 40;
      #pragma unroll
      for (int m = 0; m < 8; ++m)
        #pragma unroll
        for (int r = 0; r < 4; ++r) {
          const int tg = row0 + m * 16 + l4 * 4 + r;
          const int b = tg >> 11, t = tg & 2047;
          const size_t o = (((size_t)b * 8 + g) * 2048 + t) * 64;
          #pragma unroll
          for (int n = 0; n < 4; ++n)
            Vout[o + n * 16 + l16] = acc[m][n][r];
        }
    }
  }
}

// ---------- V transpose: Vout f32 (B,G,T,64) -> Vt bf16 (B,G,hd,T) ----------
__global__ __launch_bounds__(256) void k_vtrans(const float* __restrict__ Vout,
                                                u16* __restrict__ Vt) {
  __shared__ float tile[64][65];
  int t0 = blockIdx.x * 64;
  int bg = blockIdx.y;
  const float* src = Vout + (size_t)bg * (2048 * 64);
  #pragma unroll
  for (int p = 0; p < 16; ++p) {
    int idx = p * 256 + threadIdx.x;
    int tt = idx >> 6, d = idx & 63;
    tile[tt][d] = src[(size_t)(t0 + tt) * 64 + d];
  }
  __syncthreads();
  #pragma unroll
  for (int p = 0; p < 16; ++p) {
    int idx = p * 256 + threadIdx.x;
    int d = idx >> 6, tt = idx & 63;
    Vt[((size_t)bg * 64 + d) * 2048 + t0 + tt] = f2b(tile[tt][d]);
  }
}

// ---------- Flash attention v5: LDS-staged K/V, swizzled, 4 head-waves share ----------
__device__ __forceinline__ void pv4(const float* p, sfrag v0a, sfrag v0b,
                                    sfrag v1a, sfrag v1b,
                                    f32x16& O0, f32x16& O1, float& l) {
  unsigned w[8];
  #pragma unroll
  for (int j = 0; j < 8; ++j) w[j] = pack2(p[2 * j], p[2 * j + 1]);
  swap32(w[0], w[2]);
  swap32(w[1], w[3]);
  swap32(w[4], w[6]);
  swap32(w[5], w[7]);
  const sfrag pf0 = __builtin_bit_cast(sfrag, u32x4{w[0], w[1], w[2], w[3]});
  const sfrag pf1 = __builtin_bit_cast(sfrag, u32x4{w[4], w[5], w[6], w[7]});
  O0 = mfma32(v0a, pf0, O0);
  O0 = mfma32(v0b, pf1, O0);
  O1 = mfma32(v1a, pf0, O1);
  O1 = mfma32(v1b, pf1, O1);
  float s[8];
  #pragma unroll
  for (int j = 0; j < 8; ++j) s[j] = p[j] + p[j + 8];
  #pragma unroll
  for (int j = 0; j < 4; ++j) s[j] = s[j] + s[j + 4];
  l += (s[0] + s[1]) + (s[2] + s[3]);
}

__device__ __forceinline__ void tile64_l(const u16* __restrict__ buf,
                                         const sfrag* qf, int hi, int l31, int swz,
                                         f32x16& O0, f32x16& O1, float& l) {
  const char* Kl = (const char*)buf;
  const char* Vl = Kl + 8192;
  const int rb = l31 * 128;
  f32x16 Sa = {}, Sb = {};
  #pragma unroll
  for (int ks = 0; ks < 4; ++ks) {
    const int col = (hi * 16 + ks * 32) ^ swz;
    const sfrag ka = *(const sfrag*)(Kl + rb + col);
    const sfrag kb = *(const sfrag*)(Kl + rb + col + 4096);
    Sa = mfma32(ka, qf[ks], Sa);
    Sb = mfma32(kb, qf[ks], Sb);
  }
  float pa[16], pb[16];
  #pragma unroll
  for (int r = 0; r < 16; ++r) {
    pa[r] = __builtin_amdgcn_exp2f(Sa[r]);
    pb[r] = __builtin_amdgcn_exp2f(Sb[r]);
  }
  sfrag v0[4], v1[4];
  #pragma unroll
  for (int s = 0; s < 4; ++s) {
    const int col = (s * 32 + hi * 16) ^ swz;
    v0[s] = *(const sfrag*)(Vl + rb + col);
    v1[s] = *(const sfrag*)(Vl + rb + col + 4096);
  }
  pv4(pa, v0[0], v0[1], v1[0], v1[1], O0, O1, l);
  pv4(pb, v0[2], v0[3], v1[2], v1[3], O0, O1, l);
}

template<bool MASKED>
__device__ __forceinline__ void tile32_l(const u16* __restrict__ buf, int c,
                                         const sfrag* qf, int hi, int l31, int swz,
                                         f32x16& O0, f32x16& O1, float& l) {
  const char* Kl = (const char*)buf;
  const char* Vl = Kl + 8192;
  const int rb = l31 * 128;
  f32x16 S = {};
  #pragma unroll
  for (int ks = 0; ks < 4; ++ks) {
    const int col = (hi * 16 + ks * 32) ^ swz;
    const sfrag k = *(const sfrag*)(Kl + c * 4096 + rb + col);
    S = mfma32(k, qf[ks], S);
  }
  float p[16];
  #pragma unroll
  for (int r = 0; r < 16; ++r) {
    float s = S[r];
    if (MASKED) {
      int kvo = (r & 3) + 8 * (r >> 2) + 4 * hi;
      if (kvo > l31) s = -__builtin_inff();
    }
    p[r] = __builtin_amdgcn_exp2f(s);
  }
  const int colA = (c * 64 + hi * 16) ^ swz;
  const int colB = (c * 64 + 32 + hi * 16) ^ swz;
  const sfrag v0a = *(const sfrag*)(Vl + rb + colA);
  const sfrag v0b = *(const sfrag*)(Vl + rb + colB);
  const sfrag v1a = *(const sfrag*)(Vl + rb + colA + 4096);
  const sfrag v1b = *(const sfrag*)(Vl + rb + colB + 4096);
  pv4(p, v0a, v0b, v1a, v1b, O0, O1, l);
}

__global__ __launch_bounds__(256, 4) void k_attn5(const u16* __restrict__ Qb,
                                                  const u16* __restrict__ Kb,
                                                  const u16* __restrict__ Vt,
                                                  u16* __restrict__ attOut) {
  __shared__ u16 lds[2][8192];
  const int bid = blockIdx.x;
  const int qb = 63 - (bid >> 4);
  const int bg = bid & 15;
  const int b = bg >> 3, g = bg & 7;
  const int wave = threadIdx.x >> 6, lane = threadIdx.x & 63;
  const int h = g * 4 + wave;
  const int hi = lane >> 5, l31 = lane & 31;
  const int qrow0 = qb * 32;
  const int swz = (l31 & 7) << 4;

  const u16* Qp = Qb + (((size_t)b * 32 + h) * 2048 + qrow0 + l31) * 64 + hi * 8;
  sfrag qf[4];
  #pragma unroll
  for (int ks = 0; ks < 4; ++ks) qf[ks] = *(const sfrag*)(Qp + ks * 16);

  const char* Kg = (const char*)(Kb + ((size_t)b * 8 + g) * (2048 * 64));
  const char* Vg = (const char*)(Vt + ((size_t)b * 8 + g) * (64 * 2048));

  auto stage = [&](int bufi, int t) {
    const char* Ktile = Kg + (size_t)t * 8192;
    const char* Vtile = Vg + t * 128;
    #pragma unroll
    for (int rd = 0; rd < 2; ++rd) {
      const int p = rd * 4096 + threadIdx.x * 16;
      const int d = p >> 7;
      const int cb = (p & 127) ^ ((d & 7) << 4);
      const int lbase = rd * 4096 + wave * 1024;
      gll16(Ktile + d * 128 + cb, (char*)&lds[bufi][0] + lbase);
      gll16(Vtile + (size_t)d * 4096 + cb, (char*)&lds[bufi][0] + 8192 + lbase);
    }
  };

  f32x16 O0 = {}, O1 = {};
  float lsum = 0.f;
  const int nfull = qrow0 >> 6;
  int cur = 0;
  stage(0, 0);
  for (int t = 0; t < nfull; ++t) {
    __syncthreads();
    stage(cur ^ 1, t + 1);
    tile64_l(lds[cur], qf, hi, l31, swz, O0, O1, lsum);
    cur ^= 1;
  }
  __syncthreads();
  if (qb & 1) {
    tile32_l<false>(lds[cur], 0, qf, hi, l31, swz, O0, O1, lsum);
    tile32_l<true>(lds[cur], 1, qf, hi, l31, swz, O0, O1, lsum);
  } else {
    tile32_l<true>(lds[cur], 0, qf, hi, l31, swz, O0, O1, lsum);
  }

  const float ltot = lsum + __shfl_xor(lsum, 32);
  const float inv = 1.0f / ltot;
  const size_t orow = ((size_t)b * 2048 + qrow0 + l31) * 2048 + h * 64;
  #pragma unroll
  for (int dt = 0; dt < 2; ++dt) {
    const f32x16& O = dt ? O1 : O0;
    #pragma unroll
    for (int k = 0; k < 4; ++k) {
      ushort4 o;
      o.x = f2b(O[4 * k + 0] * inv);
      o.y = f2b(O[4 * k + 1] * inv);
      o.z = f2b(O[4 * k + 2] * inv);
      o.w = f2b(O[4 * k + 3] * inv);
      *(ushort4*)&attOut[orow + dt * 32 + 8 * k + 4 * hi] = o;
    }
  }
}

extern "C" void kernel_launch(void* const* d_in, const int* in_sizes, int n_in,
                              void* d_out, int out_size, void* d_ws, size_t ws_size,
                              hipStream_t stream) {
  const float* x  = (const float*)d_in[0];
  const float* Wq = (const float*)d_in[1];
  const float* Wk = (const float*)d_in[2];
  const float* Wv = (const float*)d_in[3];
  const float* Wo = (const float*)d_in[4];
  const int* sp   = (const int*)d_in[5];
  float* y    = (float*)d_out;            // (B,T,2048) f32
  float* Kout = y + 8388608;              // (B,G,T,64) f32
  float* Vout = y + 10485760;             // (B,G,T,64) f32

  char* ws = (char*)d_ws;
  u16*    xb     = (u16*)(ws + 0);          // 16 MiB (reused as attOut later)
  u16*    Wqkvt  = (u16*)(ws + 16777216);   // 12 MiB  (3072 x 2048 bf16, transposed)
  u16*    Wot    = (u16*)(ws + 29360128);   // 8 MiB
  float2* csn    = (float2*)(ws + 37748736);// 512 KiB (2048 x 32 cos/sin)
  u16*    Qbuf   = (u16*)(ws + 88080384);   // 16 MiB  (B,H,T,hd) bf16, pre-scaled
  u16*    Kbuf   = (u16*)(ws + 104857600);  // 4 MiB   (B,G,T,hd) bf16
  u16*    Vt     = (u16*)(ws + 109051904);  // 4 MiB   (B,G,hd,T) bf16
  u16*    attOut = xb;                      // alias: xb dead after QKV GEMM

  k_convx<<<8192, 256, 0, stream>>>(x, xb, 8388608);
  k_csn<<<256, 256, 0, stream>>>(sp, csn);
  k_convT3<<<dim3(48, 32), 256, 0, stream>>>(Wq, Wk, Wv, Wqkvt);
  k_convT<<<dim3(32, 32), 256, 0, stream>>>(Wo, Wot, 2048);
  k_gemm8<1><<<192, 512, 0, stream>>>(xb, Wqkvt, nullptr, 3072, 2048, 16,
                                      csn, Qbuf, Kbuf, Kout, Vout);
  k_vtrans<<<dim3(32, 16), 256, 0, stream>>>(Vout, Vt);
  k_attn5<<<1024, 256, 0, stream>>>(Qbuf, Kbuf, Vt, attOut);
  k_gemm8<0><<<128, 512, 0, stream>>>(attOut, Wot, y, 2048, 2048, 16,
                                      nullptr, nullptr, nullptr, nullptr, nullptr);
}

// Round 9
// 186.540 us; speedup vs baseline: 1.1721x; 1.1438x over previous
//
#include <hip/hip_runtime.h>
#include <hip/hip_bf16.h>
#include <stdint.h>

// GQA attention block, MI355X gfx950.
// R1-R4: attention ladder (swapped-QK^T, in-reg softmax, LDS-staged K/V, swizzle).
// R5-R6: 256x256 8-phase GEMM experiments (null vs 2-barrier; kept swizzle).
// R7: RoPE fused into QKV-GEMM epilogue; k_rope + QKV f32 buffer eliminated.
// R8: GEMM -> m97 shape: 128x128 tile, 4 waves, single 32KB LDS buffer, 2 barriers
//     per K-tile, no asm waits; 3-4 blocks/CU so inter-block TLP hides drains.
//     Grids 768/512 blocks (full machine) with bijective XCD chunking.

typedef __attribute__((ext_vector_type(4))) float f32x4;
typedef __attribute__((ext_vector_type(16))) float f32x16;
typedef __attribute__((ext_vector_type(8))) short sfrag;   // 8 bf16 bits
typedef __attribute__((ext_vector_type(8))) __bf16 bfrag;
typedef __attribute__((ext_vector_type(4))) unsigned int u32x4;
typedef unsigned short u16;

__device__ __forceinline__ f32x4 mfma16(sfrag a, sfrag b, f32x4 c) {
  return __builtin_amdgcn_mfma_f32_16x16x32_bf16(
      __builtin_bit_cast(bfrag, a), __builtin_bit_cast(bfrag, b), c, 0, 0, 0);
}
__device__ __forceinline__ f32x16 mfma32(sfrag a, sfrag b, f32x16 c) {
  return __builtin_amdgcn_mfma_f32_32x32x16_bf16(
      __builtin_bit_cast(bfrag, a), __builtin_bit_cast(bfrag, b), c, 0, 0, 0);
}
__device__ __forceinline__ u16 f2b(float f) {
  return __builtin_bit_cast(u16, (__bf16)f);
}
__device__ __forceinline__ unsigned pack2(float a, float b) {
  return (unsigned)f2b(a) | ((unsigned)f2b(b) << 16);
}
// a' = [a(0:31)|b(0:31)], b' = [a(32:63)|b(32:63)]
__device__ __forceinline__ void swap32(unsigned& a, unsigned& b) {
  asm("v_permlane32_swap_b32 %0, %1" : "+v"(a), "+v"(b));
}

#define GAS __attribute__((address_space(1)))
#define LAS __attribute__((address_space(3)))
__device__ __forceinline__ void gll16(const void* g, void* l) {
  __builtin_amdgcn_global_load_lds((GAS unsigned int*)g, (LAS unsigned int*)l, 16, 0, 0);
}

// ---------- f32 -> bf16 elementwise (x) ----------
__global__ __launch_bounds__(256) void k_convx(const float* __restrict__ X,
                                               u16* __restrict__ Y, int n) {
  int i = (blockIdx.x * 256 + threadIdx.x) * 4;
  if (i >= n) return;
  float4 v = *(const float4*)(X + i);
  *(ushort4*)(Y + i) = make_ushort4(f2b(v.x), f2b(v.y), f2b(v.z), f2b(v.w));
}

// ---------- cos/sin table: csn[t][j] = {cos,sin}((sp+t) * 10000^(-j/32)) ----------
__global__ __launch_bounds__(256) void k_csn(const int* __restrict__ sp,
                                             float2* __restrict__ csn) {
  const int i = blockIdx.x * 256 + threadIdx.x;   // 65536 = 2048 x 32
  const int t = i >> 5, j = i & 31;
  const float freq = powf(10000.0f, -(float)j * (1.0f / 32.0f));
  const float ang = (float)(sp[0] + t) * freq;
  csn[i] = make_float2(cosf(ang), sinf(ang));
}

// ---------- Wq|Wk|Wv (2048 x N) f32 -> Wt (3072 x 2048) bf16 transposed ----------
__global__ __launch_bounds__(256) void k_convT3(const float* __restrict__ Wq,
                                                const float* __restrict__ Wk,
                                                const float* __restrict__ Wv,
                                                u16* __restrict__ Wt) {
  __shared__ float tile[64][65];
  const int n0g = blockIdx.x * 64;   // 0..3071 (global output row)
  const float* W; int N, n0;
  if (n0g < 2048)      { W = Wq; N = 2048; n0 = n0g; }
  else if (n0g < 2560) { W = Wk; N = 512;  n0 = n0g - 2048; }
  else                 { W = Wv; N = 512;  n0 = n0g - 2560; }
  const int k0 = blockIdx.y * 64;
  #pragma unroll
  for (int p = 0; p < 16; ++p) {
    int idx = p * 256 + threadIdx.x;
    int kk = idx >> 6, nn = idx & 63;
    tile[kk][nn] = W[(size_t)(k0 + kk) * N + n0 + nn];
  }
  __syncthreads();
  #pragma unroll
  for (int p = 0; p < 16; ++p) {
    int idx = p * 256 + threadIdx.x;
    int nn = idx >> 6, kk = idx & 63;
    Wt[(size_t)(n0g + nn) * 2048 + k0 + kk] = f2b(tile[kk][nn]);
  }
}

// ---------- Wo (2048 x 2048) f32 -> Wot bf16 transposed ----------
__global__ __launch_bounds__(256) void k_convT(const float* __restrict__ W,
                                               u16* __restrict__ Wt, int N) {
  __shared__ float tile[64][65];
  int n0 = blockIdx.x * 64, k0 = blockIdx.y * 64;
  #pragma unroll
  for (int p = 0; p < 16; ++p) {
    int idx = p * 256 + threadIdx.x;
    int kk = idx >> 6, nn = idx & 63;
    tile[kk][nn] = W[(size_t)(k0 + kk) * N + n0 + nn];
  }
  __syncthreads();
  #pragma unroll
  for (int p = 0; p < 16; ++p) {
    int idx = p * 256 + threadIdx.x;
    int nn = idx >> 6, kk = idx & 63;
    Wt[(size_t)(n0 + nn) * 2048 + k0 + kk] = f2b(tile[kk][nn]);
  }
}

// ---------- GEMM 128x128/BK=64, 4 waves, single-buffer m97 structure ----------
// C(MxN f32) = A(MxK bf16) * Bt(NxK bf16)^T.  Grid 1D, XCD-chunked (nwg%8==0).
// LDS 32KB: A [128 rows][128B] at 0, B same at 16384; rows hold K-64 contiguous,
// XOR-swizzled byte ^= ((row&7)<<4) on BOTH stage-source and frag-read.
// Loop: { stage(t); __syncthreads(); compute; __syncthreads(); } — inter-block
// TLP (3-4 blocks/CU) hides the drain, per m97/m114.
// MODE 0: plain C write (out-proj). MODE 1: fused RoPE epilogue (QKV); this
// wave's 64 cols = head bx*2+wn; pair (j,j+32) = acc[m][n]/acc[m][n+2].
template<int MODE>
__global__ __launch_bounds__(256, 3) void k_gemm128(const u16* __restrict__ A,
                                                    const u16* __restrict__ Bt,
                                                    float* __restrict__ C,
                                                    int N, int K, int GY,
                                                    const float2* __restrict__ csn,
                                                    u16* __restrict__ Qb,
                                                    u16* __restrict__ Kb,
                                                    float* __restrict__ Kout,
                                                    float* __restrict__ Vout) {
  __shared__ u16 lds[16384];                    // 32 KB
  char* const L = (char*)&lds[0];
  const int tid = threadIdx.x;
  const int q8 = gridDim.x >> 3;                // nwg % 8 == 0 (bijective)
  const int id2 = (blockIdx.x & 7) * q8 + (blockIdx.x >> 3);
  const int by = id2 % GY, bx = id2 / GY;       // consecutive id2 share bx (B-panel)
  const int wid = tid >> 6, lane = tid & 63;
  const int wm = wid >> 1, wn = wid & 1;        // 2 x 2 waves, 64x64 C each
  const int l16 = lane & 15, l4 = lane >> 4;
  const size_t K2 = (size_t)K * 2;
  const char* Ab = (const char*)(A + (size_t)(by * 128) * K);
  const char* Bb = (const char*)(Bt + (size_t)(bx * 128) * K);
  const int NT = K >> 6;

  auto stage = [&](const char* gb, int reg, int t) {
    #pragma unroll
    for (int ld = 0; ld < 4; ++ld) {
      const int p = ld * 4096 + tid * 16;
      const int r = p >> 7;
      const int cb = (p & 127) ^ ((r & 7) << 4);
      gll16(gb + (size_t)r * K2 + (size_t)t * 128 + cb, L + reg + p);
    }
  };

  const int swz = (l16 & 7) << 4;
  const int c0 = (l4 * 16) ^ swz;               // k-half 0
  const int c1 = (64 + l4 * 16) ^ swz;          // k-half 1
  const int aOff = (wm * 64 + l16) * 128;
  const int bOff = 16384 + (wn * 64 + l16) * 128;

  f32x4 acc[4][4];
  #pragma unroll
  for (int m = 0; m < 4; ++m)
    #pragma unroll
    for (int n = 0; n < 4; ++n) acc[m][n] = f32x4{0.f, 0.f, 0.f, 0.f};

  for (int t = 0; t < NT; ++t) {
    stage(Ab, 0, t);
    stage(Bb, 16384, t);
    __syncthreads();                            // drains vmcnt -> staged data visible
    sfrag a0[4], a1[4], b0[4], b1[4];
    #pragma unroll
    for (int m = 0; m < 4; ++m) {
      a0[m] = *(const sfrag*)(L + aOff + m * 2048 + c0);
      a1[m] = *(const sfrag*)(L + aOff + m * 2048 + c1);
    }
    #pragma unroll
    for (int n = 0; n < 4; ++n) {
      b0[n] = *(const sfrag*)(L + bOff + n * 2048 + c0);
      b1[n] = *(const sfrag*)(L + bOff + n * 2048 + c1);
    }
    #pragma unroll
    for (int m = 0; m < 4; ++m)
      #pragma unroll
      for (int n = 0; n < 4; ++n) {
        acc[m][n] = mfma16(a0[m], b0[n], acc[m][n]);
        acc[m][n] = mfma16(a1[m], b1[n], acc[m][n]);
      }
    __syncthreads();                            // protect buffer overwrite
  }

  if constexpr (MODE == 0) {
    float* Cb = C + (size_t)(by * 128 + wm * 64) * N + bx * 128 + wn * 64;
    #pragma unroll
    for (int m = 0; m < 4; ++m)
      #pragma unroll
      for (int n = 0; n < 4; ++n)
        #pragma unroll
        for (int r = 0; r < 4; ++r)
          Cb[(size_t)(m * 16 + l4 * 4 + r) * N + n * 16 + l16] = acc[m][n][r];
  } else {
    // Fused RoPE + layout. This wave's 64 cols = head (bx*2+wn).
    const int head = bx * 2 + wn;
    const int row0 = by * 128 + wm * 64;
    if (head < 40) {                    // Q (0..31) or K (32..39): rope
      const float QS = 0.125f * 1.44269504f;   // 1/sqrt(hd) * log2(e)
      #pragma unroll
      for (int m = 0; m < 4; ++m)
        #pragma unroll
        for (int r = 0; r < 4; ++r) {
          const int tg = row0 + m * 16 + l4 * 4 + r;
          const int b = tg >> 11, t = tg & 2047;
          #pragma unroll
          for (int n = 0; n < 2; ++n) {
            const int j = n * 16 + l16;
            const float2 cz = csn[t * 32 + j];
            const float x1 = acc[m][n][r], x2 = acc[m][n + 2][r];
            const float o1 = x1 * cz.x - x2 * cz.y;
            const float o2 = x1 * cz.y + x2 * cz.x;
            if (head < 32) {
              const size_t o = (((size_t)b * 32 + head) * 2048 + t) * 64 + j;
              Qb[o] = f2b(o1 * QS);
              Qb[o + 32] = f2b(o2 * QS);
            } else {
              const int g = head - 32;
              const size_t o = (((size_t)b * 8 + g) * 2048 + t) * 64 + j;
              Kb[o] = f2b(o1);  Kb[o + 32] = f2b(o2);
              Kout[o] = o1;     Kout[o + 32] = o2;
            }
          }
        }
    } else {                            // V (40..47): plain copy-out f32
      const int g = head - 40;
      #pragma unroll
      for (int m = 0; m < 4; ++m)
        #pragma unroll
        for (int r = 0; r < 4; ++r) {
          const int tg = row0 + m * 16 + l4 * 4 + r;
          const int b = tg >> 11, t = tg & 2047;
          const size_t o = (((size_t)b * 8 + g) * 2048 + t) * 64;
          #pragma unroll
          for (int n = 0; n < 4; ++n)
            Vout[o + n * 16 + l16] = acc[m][n][r];
        }
    }
  }
}

// ---------- V transpose: Vout f32 (B,G,T,64) -> Vt bf16 (B,G,hd,T) ----------
__global__ __launch_bounds__(256) void k_vtrans(const float* __restrict__ Vout,
                                                u16* __restrict__ Vt) {
  __shared__ float tile[64][65];
  int t0 = blockIdx.x * 64;
  int bg = blockIdx.y;
  const float* src = Vout + (size_t)bg * (2048 * 64);
  #pragma unroll
  for (int p = 0; p < 16; ++p) {
    int idx = p * 256 + threadIdx.x;
    int tt = idx >> 6, d = idx & 63;
    tile[tt][d] = src[(size_t)(t0 + tt) * 64 + d];
  }
  __syncthreads();
  #pragma unroll
  for (int p = 0; p < 16; ++p) {
    int idx = p * 256 + threadIdx.x;
    int d = idx >> 6, tt = idx & 63;
    Vt[((size_t)bg * 64 + d) * 2048 + t0 + tt] = f2b(tile[tt][d]);
  }
}

// ---------- Flash attention v5: LDS-staged K/V, swizzled, 4 head-waves share ----------
__device__ __forceinline__ void pv4(const float* p, sfrag v0a, sfrag v0b,
                                    sfrag v1a, sfrag v1b,
                                    f32x16& O0, f32x16& O1, float& l) {
  unsigned w[8];
  #pragma unroll
  for (int j = 0; j < 8; ++j) w[j] = pack2(p[2 * j], p[2 * j + 1]);
  swap32(w[0], w[2]);
  swap32(w[1], w[3]);
  swap32(w[4], w[6]);
  swap32(w[5], w[7]);
  const sfrag pf0 = __builtin_bit_cast(sfrag, u32x4{w[0], w[1], w[2], w[3]});
  const sfrag pf1 = __builtin_bit_cast(sfrag, u32x4{w[4], w[5], w[6], w[7]});
  O0 = mfma32(v0a, pf0, O0);
  O0 = mfma32(v0b, pf1, O0);
  O1 = mfma32(v1a, pf0, O1);
  O1 = mfma32(v1b, pf1, O1);
  float s[8];
  #pragma unroll
  for (int j = 0; j < 8; ++j) s[j] = p[j] + p[j + 8];
  #pragma unroll
  for (int j = 0; j < 4; ++j) s[j] = s[j] + s[j + 4];
  l += (s[0] + s[1]) + (s[2] + s[3]);
}

__device__ __forceinline__ void tile64_l(const u16* __restrict__ buf,
                                         const sfrag* qf, int hi, int l31, int swz,
                                         f32x16& O0, f32x16& O1, float& l) {
  const char* Kl = (const char*)buf;
  const char* Vl = Kl + 8192;
  const int rb = l31 * 128;
  f32x16 Sa = {}, Sb = {};
  #pragma unroll
  for (int ks = 0; ks < 4; ++ks) {
    const int col = (hi * 16 + ks * 32) ^ swz;
    const sfrag ka = *(const sfrag*)(Kl + rb + col);
    const sfrag kb = *(const sfrag*)(Kl + rb + col + 4096);
    Sa = mfma32(ka, qf[ks], Sa);
    Sb = mfma32(kb, qf[ks], Sb);
  }
  float pa[16], pb[16];
  #pragma unroll
  for (int r = 0; r < 16; ++r) {
    pa[r] = __builtin_amdgcn_exp2f(Sa[r]);
    pb[r] = __builtin_amdgcn_exp2f(Sb[r]);
  }
  sfrag v0[4], v1[4];
  #pragma unroll
  for (int s = 0; s < 4; ++s) {
    const int col = (s * 32 + hi * 16) ^ swz;
    v0[s] = *(const sfrag*)(Vl + rb + col);
    v1[s] = *(const sfrag*)(Vl + rb + col + 4096);
  }
  pv4(pa, v0[0], v0[1], v1[0], v1[1], O0, O1, l);
  pv4(pb, v0[2], v0[3], v1[2], v1[3], O0, O1, l);
}

template<bool MASKED>
__device__ __forceinline__ void tile32_l(const u16* __restrict__ buf, int c,
                                         const sfrag* qf, int hi, int l31, int swz,
                                         f32x16& O0, f32x16& O1, float& l) {
  const char* Kl = (const char*)buf;
  const char* Vl = Kl + 8192;
  const int rb = l31 * 128;
  f32x16 S = {};
  #pragma unroll
  for (int ks = 0; ks < 4; ++ks) {
    const int col = (hi * 16 + ks * 32) ^ swz;
    const sfrag k = *(const sfrag*)(Kl + c * 4096 + rb + col);
    S = mfma32(k, qf[ks], S);
  }
  float p[16];
  #pragma unroll
  for (int r = 0; r < 16; ++r) {
    float s = S[r];
    if (MASKED) {
      int kvo = (r & 3) + 8 * (r >> 2) + 4 * hi;
      if (kvo > l31) s = -__builtin_inff();
    }
    p[r] = __builtin_amdgcn_exp2f(s);
  }
  const int colA = (c * 64 + hi * 16) ^ swz;
  const int colB = (c * 64 + 32 + hi * 16) ^ swz;
  const sfrag v0a = *(const sfrag*)(Vl + rb + colA);
  const sfrag v0b = *(const sfrag*)(Vl + rb + colB);
  const sfrag v1a = *(const sfrag*)(Vl + rb + colA + 4096);
  const sfrag v1b = *(const sfrag*)(Vl + rb + colB + 4096);
  pv4(p, v0a, v0b, v1a, v1b, O0, O1, l);
}

__global__ __launch_bounds__(256, 4) void k_attn5(const u16* __restrict__ Qb,
                                                  const u16* __restrict__ Kb,
                                                  const u16* __restrict__ Vt,
                                                  u16* __restrict__ attOut) {
  __shared__ u16 lds[2][8192];
  const int bid = blockIdx.x;
  const int qb = 63 - (bid >> 4);
  const int bg = bid & 15;
  const int b = bg >> 3, g = bg & 7;
  const int wave = threadIdx.x >> 6, lane = threadIdx.x & 63;
  const int h = g * 4 + wave;
  const int hi = lane >> 5, l31 = lane & 31;
  const int qrow0 = qb * 32;
  const int swz = (l31 & 7) << 4;

  const u16* Qp = Qb + (((size_t)b * 32 + h) * 2048 + qrow0 + l31) * 64 + hi * 8;
  sfrag qf[4];
  #pragma unroll
  for (int ks = 0; ks < 4; ++ks) qf[ks] = *(const sfrag*)(Qp + ks * 16);

  const char* Kg = (const char*)(Kb + ((size_t)b * 8 + g) * (2048 * 64));
  const char* Vg = (const char*)(Vt + ((size_t)b * 8 + g) * (64 * 2048));

  auto stage = [&](int bufi, int t) {
    const char* Ktile = Kg + (size_t)t * 8192;
    const char* Vtile = Vg + t * 128;
    #pragma unroll
    for (int rd = 0; rd < 2; ++rd) {
      const int p = rd * 4096 + threadIdx.x * 16;
      const int d = p >> 7;
      const int cb = (p & 127) ^ ((d & 7) << 4);
      const int lbase = rd * 4096 + wave * 1024;
      gll16(Ktile + d * 128 + cb, (char*)&lds[bufi][0] + lbase);
      gll16(Vtile + (size_t)d * 4096 + cb, (char*)&lds[bufi][0] + 8192 + lbase);
    }
  };

  f32x16 O0 = {}, O1 = {};
  float lsum = 0.f;
  const int nfull = qrow0 >> 6;
  int cur = 0;
  stage(0, 0);
  for (int t = 0; t < nfull; ++t) {
    __syncthreads();
    stage(cur ^ 1, t + 1);
    tile64_l(lds[cur], qf, hi, l31, swz, O0, O1, lsum);
    cur ^= 1;
  }
  __syncthreads();
  if (qb & 1) {
    tile32_l<false>(lds[cur], 0, qf, hi, l31, swz, O0, O1, lsum);
    tile32_l<true>(lds[cur], 1, qf, hi, l31, swz, O0, O1, lsum);
  } else {
    tile32_l<true>(lds[cur], 0, qf, hi, l31, swz, O0, O1, lsum);
  }

  const float ltot = lsum + __shfl_xor(lsum, 32);
  const float inv = 1.0f / ltot;
  const size_t orow = ((size_t)b * 2048 + qrow0 + l31) * 2048 + h * 64;
  #pragma unroll
  for (int dt = 0; dt < 2; ++dt) {
    const f32x16& O = dt ? O1 : O0;
    #pragma unroll
    for (int k = 0; k < 4; ++k) {
      ushort4 o;
      o.x = f2b(O[4 * k + 0] * inv);
      o.y = f2b(O[4 * k + 1] * inv);
      o.z = f2b(O[4 * k + 2] * inv);
      o.w = f2b(O[4 * k + 3] * inv);
      *(ushort4*)&attOut[orow + dt * 32 + 8 * k + 4 * hi] = o;
    }
  }
}

extern "C" void kernel_launch(void* const* d_in, const int* in_sizes, int n_in,
                              void* d_out, int out_size, void* d_ws, size_t ws_size,
                              hipStream_t stream) {
  const float* x  = (const float*)d_in[0];
  const float* Wq = (const float*)d_in[1];
  const float* Wk = (const float*)d_in[2];
  const float* Wv = (const float*)d_in[3];
  const float* Wo = (const float*)d_in[4];
  const int* sp   = (const int*)d_in[5];
  float* y    = (float*)d_out;            // (B,T,2048) f32
  float* Kout = y + 8388608;              // (B,G,T,64) f32
  float* Vout = y + 10485760;             // (B,G,T,64) f32

  char* ws = (char*)d_ws;
  u16*    xb     = (u16*)(ws + 0);          // 16 MiB (reused as attOut later)
  u16*    Wqkvt  = (u16*)(ws + 16777216);   // 12 MiB  (3072 x 2048 bf16, transposed)
  u16*    Wot    = (u16*)(ws + 29360128);   // 8 MiB
  float2* csn    = (float2*)(ws + 37748736);// 512 KiB (2048 x 32 cos/sin)
  u16*    Qbuf   = (u16*)(ws + 88080384);   // 16 MiB  (B,H,T,hd) bf16, pre-scaled
  u16*    Kbuf   = (u16*)(ws + 104857600);  // 4 MiB   (B,G,T,hd) bf16
  u16*    Vt     = (u16*)(ws + 109051904);  // 4 MiB   (B,G,hd,T) bf16
  u16*    attOut = xb;                      // alias: xb dead after QKV GEMM

  k_convx<<<8192, 256, 0, stream>>>(x, xb, 8388608);
  k_csn<<<256, 256, 0, stream>>>(sp, csn);
  k_convT3<<<dim3(48, 32), 256, 0, stream>>>(Wq, Wk, Wv, Wqkvt);
  k_convT<<<dim3(32, 32), 256, 0, stream>>>(Wo, Wot, 2048);
  k_gemm128<1><<<768, 256, 0, stream>>>(xb, Wqkvt, nullptr, 3072, 2048, 32,
                                        csn, Qbuf, Kbuf, Kout, Vout);
  k_vtrans<<<dim3(32, 16), 256, 0, stream>>>(Vout, Vt);
  k_attn5<<<1024, 256, 0, stream>>>(Qbuf, Kbuf, Vt, attOut);
  k_gemm128<0><<<512, 256, 0, stream>>>(attOut, Wot, y, 2048, 2048, 32,
                                        nullptr, nullptr, nullptr, nullptr, nullptr);
}

// Round 10
// 184.941 us; speedup vs baseline: 1.1823x; 1.0086x over previous
//
#include <hip/hip_runtime.h>
#include <hip/hip_bf16.h>
#include <stdint.h>

// GQA attention block, MI355X gfx950.
// R1-R4: attention ladder (swapped-QK^T, in-reg softmax, LDS-staged K/V, swizzle).
// R5-R7: GEMM schedule experiments (256^2/8-phase null); RoPE fused into QKV GEMM.
// R8: GEMM -> m97 128x128 shape, 3 blocks/CU; inter-block TLP hides barrier drains.
// R9: vectorized+merged weight transposes (float4/ushort4); csn merged into convx;
//     gemm<1> Q/K epilogue via LDS bounce -> coalesced 1KB row stores.

typedef __attribute__((ext_vector_type(4))) float f32x4;
typedef __attribute__((ext_vector_type(16))) float f32x16;
typedef __attribute__((ext_vector_type(8))) short sfrag;   // 8 bf16 bits
typedef __attribute__((ext_vector_type(8))) __bf16 bfrag;
typedef __attribute__((ext_vector_type(4))) unsigned int u32x4;
typedef unsigned short u16;

__device__ __forceinline__ f32x4 mfma16(sfrag a, sfrag b, f32x4 c) {
  return __builtin_amdgcn_mfma_f32_16x16x32_bf16(
      __builtin_bit_cast(bfrag, a), __builtin_bit_cast(bfrag, b), c, 0, 0, 0);
}
__device__ __forceinline__ f32x16 mfma32(sfrag a, sfrag b, f32x16 c) {
  return __builtin_amdgcn_mfma_f32_32x32x16_bf16(
      __builtin_bit_cast(bfrag, a), __builtin_bit_cast(bfrag, b), c, 0, 0, 0);
}
__device__ __forceinline__ u16 f2b(float f) {
  return __builtin_bit_cast(u16, (__bf16)f);
}
__device__ __forceinline__ unsigned pack2(float a, float b) {
  return (unsigned)f2b(a) | ((unsigned)f2b(b) << 16);
}
// a' = [a(0:31)|b(0:31)], b' = [a(32:63)|b(32:63)]
__device__ __forceinline__ void swap32(unsigned& a, unsigned& b) {
  asm("v_permlane32_swap_b32 %0, %1" : "+v"(a), "+v"(b));
}

#define GAS __attribute__((address_space(1)))
#define LAS __attribute__((address_space(3)))
__device__ __forceinline__ void gll16(const void* g, void* l) {
  __builtin_amdgcn_global_load_lds((GAS unsigned int*)g, (LAS unsigned int*)l, 16, 0, 0);
}

// ---------- x f32 -> bf16 (blocks 0..8191) + cos/sin table (blocks 8192..8447) ----------
__global__ __launch_bounds__(256) void k_convx(const float* __restrict__ X,
                                               u16* __restrict__ Y,
                                               const int* __restrict__ sp,
                                               float2* __restrict__ csn) {
  const int bid = blockIdx.x;
  if (bid < 8192) {
    const int i = (bid * 256 + threadIdx.x) * 4;
    float4 v = *(const float4*)(X + i);
    *(ushort4*)(Y + i) = make_ushort4(f2b(v.x), f2b(v.y), f2b(v.z), f2b(v.w));
  } else {
    const int i = (bid - 8192) * 256 + threadIdx.x;   // 65536 = 2048 x 32
    const int t = i >> 5, j = i & 31;
    const float freq = powf(10000.0f, -(float)j * (1.0f / 32.0f));
    const float ang = (float)(sp[0] + t) * freq;
    csn[i] = make_float2(cosf(ang), sinf(ang));
  }
}

// ---------- all weight transposes, vectorized: float4 reads, ushort4 writes ----------
// bx 0..31: Wq -> Wqkvt rows 0..2047 ; 32..39: Wk -> rows 2048.. ; 40..47: Wv -> 2560..
// bx 48..79: Wo -> Wot rows 0..2047.
__global__ __launch_bounds__(256) void k_convTall(const float* __restrict__ Wq,
                                                  const float* __restrict__ Wk,
                                                  const float* __restrict__ Wv,
                                                  const float* __restrict__ Wo,
                                                  u16* __restrict__ Wqkvt,
                                                  u16* __restrict__ Wot) {
  __shared__ float tile[64][65];
  const int bx = blockIdx.x;
  const int k0 = blockIdx.y * 64;
  const float* W; int N, n0; u16* Dst; int nd;
  if (bx < 32)      { W = Wq; N = 2048; n0 = bx * 64;        Dst = Wqkvt; nd = n0; }
  else if (bx < 40) { W = Wk; N = 512;  n0 = (bx - 32) * 64; Dst = Wqkvt; nd = 2048 + n0; }
  else if (bx < 48) { W = Wv; N = 512;  n0 = (bx - 40) * 64; Dst = Wqkvt; nd = 2560 + n0; }
  else              { W = Wo; N = 2048; n0 = (bx - 48) * 64; Dst = Wot;   nd = n0; }
  const int tid = threadIdx.x;
  #pragma unroll
  for (int it = 0; it < 4; ++it) {
    const int idx = it * 256 + tid;          // 0..1023
    const int kk = idx >> 4, nq = idx & 15;
    float4 v = *(const float4*)(W + (size_t)(k0 + kk) * N + n0 + nq * 4);
    tile[kk][nq * 4 + 0] = v.x;
    tile[kk][nq * 4 + 1] = v.y;
    tile[kk][nq * 4 + 2] = v.z;
    tile[kk][nq * 4 + 3] = v.w;
  }
  __syncthreads();
  #pragma unroll
  for (int it = 0; it < 4; ++it) {
    const int idx = it * 256 + tid;
    const int nn = idx >> 4, kq = idx & 15;
    ushort4 o;
    o.x = f2b(tile[kq * 4 + 0][nn]);
    o.y = f2b(tile[kq * 4 + 1][nn]);
    o.z = f2b(tile[kq * 4 + 2][nn]);
    o.w = f2b(tile[kq * 4 + 3][nn]);
    *(ushort4*)(Dst + (size_t)(nd + nn) * 2048 + k0 + kq * 4) = o;
  }
}

// ---------- GEMM 128x128/BK=64, 4 waves, single-buffer m97 structure ----------
// C(MxN f32) = A(MxK bf16) * Bt(NxK bf16)^T.  Grid 1D, XCD-chunked (nwg%8==0).
// LDS 32KB: A [128 rows][128B] at 0, B at 16384; XOR swizzle byte ^= ((row&7)<<4)
// on BOTH stage-source and frag-read.  MODE 0: plain C write (out-proj).
// MODE 1 (QKV): fused RoPE; wave's 64 cols = head bx*2+wn; Q/K bf16 written via
// per-wave LDS bounce (8KB each, post-loop) -> coalesced 1KB row stores;
// Kout/Vout f32 stay direct.  Blocks are head-homogeneous (head<40 <=> bx<20).
template<int MODE>
__global__ __launch_bounds__(256, 3) void k_gemm128(const u16* __restrict__ A,
                                                    const u16* __restrict__ Bt,
                                                    float* __restrict__ C,
                                                    int N, int K, int GY,
                                                    const float2* __restrict__ csn,
                                                    u16* __restrict__ Qb,
                                                    u16* __restrict__ Kb,
                                                    float* __restrict__ Kout,
                                                    float* __restrict__ Vout) {
  __shared__ u16 lds[16384];                    // 32 KB
  char* const L = (char*)&lds[0];
  const int tid = threadIdx.x;
  const int q8 = gridDim.x >> 3;                // nwg % 8 == 0 (bijective)
  const int id2 = (blockIdx.x & 7) * q8 + (blockIdx.x >> 3);
  const int by = id2 % GY, bx = id2 / GY;
  const int wid = tid >> 6, lane = tid & 63;
  const int wm = wid >> 1, wn = wid & 1;        // 2 x 2 waves, 64x64 C each
  const int l16 = lane & 15, l4 = lane >> 4;
  const size_t K2 = (size_t)K * 2;
  const char* Ab = (const char*)(A + (size_t)(by * 128) * K);
  const char* Bb = (const char*)(Bt + (size_t)(bx * 128) * K);
  const int NT = K >> 6;

  auto stage = [&](const char* gb, int reg, int t) {
    #pragma unroll
    for (int ld = 0; ld < 4; ++ld) {
      const int p = ld * 4096 + tid * 16;
      const int r = p >> 7;
      const int cb = (p & 127) ^ ((r & 7) << 4);
      gll16(gb + (size_t)r * K2 + (size_t)t * 128 + cb, L + reg + p);
    }
  };

  const int swz = (l16 & 7) << 4;
  const int c0 = (l4 * 16) ^ swz;               // k-half 0
  const int c1 = (64 + l4 * 16) ^ swz;          // k-half 1
  const int aOff = (wm * 64 + l16) * 128;
  const int bOff = 16384 + (wn * 64 + l16) * 128;

  f32x4 acc[4][4];
  #pragma unroll
  for (int m = 0; m < 4; ++m)
    #pragma unroll
    for (int n = 0; n < 4; ++n) acc[m][n] = f32x4{0.f, 0.f, 0.f, 0.f};

  for (int t = 0; t < NT; ++t) {
    stage(Ab, 0, t);
    stage(Bb, 16384, t);
    __syncthreads();                            // drains vmcnt -> staged data visible
    sfrag a0[4], a1[4], b0[4], b1[4];
    #pragma unroll
    for (int m = 0; m < 4; ++m) {
      a0[m] = *(const sfrag*)(L + aOff + m * 2048 + c0);
      a1[m] = *(const sfrag*)(L + aOff + m * 2048 + c1);
    }
    #pragma unroll
    for (int n = 0; n < 4; ++n) {
      b0[n] = *(const sfrag*)(L + bOff + n * 2048 + c0);
      b1[n] = *(const sfrag*)(L + bOff + n * 2048 + c1);
    }
    #pragma unroll
    for (int m = 0; m < 4; ++m)
      #pragma unroll
      for (int n = 0; n < 4; ++n) {
        acc[m][n] = mfma16(a0[m], b0[n], acc[m][n]);
        acc[m][n] = mfma16(a1[m], b1[n], acc[m][n]);
      }
    __syncthreads();                            // protect buffer overwrite
  }

  if constexpr (MODE == 0) {
    float* Cb = C + (size_t)(by * 128 + wm * 64) * N + bx * 128 + wn * 64;
    #pragma unroll
    for (int m = 0; m < 4; ++m)
      #pragma unroll
      for (int n = 0; n < 4; ++n)
        #pragma unroll
        for (int r = 0; r < 4; ++r)
          Cb[(size_t)(m * 16 + l4 * 4 + r) * N + n * 16 + l16] = acc[m][n][r];
  } else {
    const int head = bx * 2 + wn;
    const int row0 = by * 128 + wm * 64;
    if (head < 40) {                    // Q (0..31) or K (32..39): rope + LDS bounce
      u16* Lw = (u16*)(L + wid * 8192);          // this wave's 64x64 bf16 tile
      const float QS = 0.125f * 1.44269504f;     // 1/sqrt(hd) * log2(e)
      const bool isQ = head < 32;
      #pragma unroll
      for (int m = 0; m < 4; ++m)
        #pragma unroll
        for (int r = 0; r < 4; ++r) {
          const int tl = m * 16 + l4 * 4 + r;
          const int tg = row0 + tl;
          const int b = tg >> 11, t = tg & 2047;
          #pragma unroll
          for (int n = 0; n < 2; ++n) {
            const int j = n * 16 + l16;
            const float2 cz = csn[t * 32 + j];
            const float x1 = acc[m][n][r], x2 = acc[m][n + 2][r];
            const float o1 = x1 * cz.x - x2 * cz.y;
            const float o2 = x1 * cz.y + x2 * cz.x;
            if (isQ) {
              Lw[tl * 64 + j]      = f2b(o1 * QS);
              Lw[tl * 64 + j + 32] = f2b(o2 * QS);
            } else {
              Lw[tl * 64 + j]      = f2b(o1);
              Lw[tl * 64 + j + 32] = f2b(o2);
              const int g = head - 32;
              const size_t o = (((size_t)b * 8 + g) * 2048 + t) * 64 + j;
              Kout[o] = o1;  Kout[o + 32] = o2;
            }
          }
        }
      __syncthreads();   // block-uniform here (head<40 <=> bx<20); orders LDS w->r
      u16* dst = isQ ? Qb : Kb;
      const int hh = isQ ? head : (head - 32);
      const int hstride = isQ ? 32 : 8;
      #pragma unroll
      for (int it = 0; it < 8; ++it) {
        const int tl = it * 8 + (lane >> 3);
        const int col = (lane & 7) * 8;          // u16 units, 16B chunk
        const u32x4 v = *(const u32x4*)&Lw[tl * 64 + col];
        const int tg = row0 + tl;
        const int b = tg >> 11, t = tg & 2047;
        *(u32x4*)(dst + (((size_t)b * hstride + hh) * 2048 + t) * 64 + col) = v;
      }
    } else {                            // V (40..47): plain copy-out f32
      const int g = head - 40;
      #pragma unroll
      for (int m = 0; m < 4; ++m)
        #pragma unroll
        for (int r = 0; r < 4; ++r) {
          const int tg = row0 + m * 16 + l4 * 4 + r;
          const int b = tg >> 11, t = tg & 2047;
          const size_t o = (((size_t)b * 8 + g) * 2048 + t) * 64;
          #pragma unroll
          for (int n = 0; n < 4; ++n)
            Vout[o + n * 16 + l16] = acc[m][n][r];
        }
    }
  }
}

// ---------- V transpose: Vout f32 (B,G,T,64) -> Vt bf16 (B,G,hd,T) ----------
__global__ __launch_bounds__(256) void k_vtrans(const float* __restrict__ Vout,
                                                u16* __restrict__ Vt) {
  __shared__ float tile[64][65];
  int t0 = blockIdx.x * 64;
  int bg = blockIdx.y;
  const float* src = Vout + (size_t)bg * (2048 * 64);
  #pragma unroll
  for (int p = 0; p < 16; ++p) {
    int idx = p * 256 + threadIdx.x;
    int tt = idx >> 6, d = idx & 63;
    tile[tt][d] = src[(size_t)(t0 + tt) * 64 + d];
  }
  __syncthreads();
  #pragma unroll
  for (int p = 0; p < 16; ++p) {
    int idx = p * 256 + threadIdx.x;
    int d = idx >> 6, tt = idx & 63;
    Vt[((size_t)bg * 64 + d) * 2048 + t0 + tt] = f2b(tile[tt][d]);
  }
}

// ---------- Flash attention v5: LDS-staged K/V, swizzled, 4 head-waves share ----------
__device__ __forceinline__ void pv4(const float* p, sfrag v0a, sfrag v0b,
                                    sfrag v1a, sfrag v1b,
                                    f32x16& O0, f32x16& O1, float& l) {
  unsigned w[8];
  #pragma unroll
  for (int j = 0; j < 8; ++j) w[j] = pack2(p[2 * j], p[2 * j + 1]);
  swap32(w[0], w[2]);
  swap32(w[1], w[3]);
  swap32(w[4], w[6]);
  swap32(w[5], w[7]);
  const sfrag pf0 = __builtin_bit_cast(sfrag, u32x4{w[0], w[1], w[2], w[3]});
  const sfrag pf1 = __builtin_bit_cast(sfrag, u32x4{w[4], w[5], w[6], w[7]});
  O0 = mfma32(v0a, pf0, O0);
  O0 = mfma32(v0b, pf1, O0);
  O1 = mfma32(v1a, pf0, O1);
  O1 = mfma32(v1b, pf1, O1);
  float s[8];
  #pragma unroll
  for (int j = 0; j < 8; ++j) s[j] = p[j] + p[j + 8];
  #pragma unroll
  for (int j = 0; j < 4; ++j) s[j] = s[j] + s[j + 4];
  l += (s[0] + s[1]) + (s[2] + s[3]);
}

__device__ __forceinline__ void tile64_l(const u16* __restrict__ buf,
                                         const sfrag* qf, int hi, int l31, int swz,
                                         f32x16& O0, f32x16& O1, float& l) {
  const char* Kl = (const char*)buf;
  const char* Vl = Kl + 8192;
  const int rb = l31 * 128;
  f32x16 Sa = {}, Sb = {};
  #pragma unroll
  for (int ks = 0; ks < 4; ++ks) {
    const int col = (hi * 16 + ks * 32) ^ swz;
    const sfrag ka = *(const sfrag*)(Kl + rb + col);
    const sfrag kb = *(const sfrag*)(Kl + rb + col + 4096);
    Sa = mfma32(ka, qf[ks], Sa);
    Sb = mfma32(kb, qf[ks], Sb);
  }
  float pa[16], pb[16];
  #pragma unroll
  for (int r = 0; r < 16; ++r) {
    pa[r] = __builtin_amdgcn_exp2f(Sa[r]);
    pb[r] = __builtin_amdgcn_exp2f(Sb[r]);
  }
  sfrag v0[4], v1[4];
  #pragma unroll
  for (int s = 0; s < 4; ++s) {
    const int col = (s * 32 + hi * 16) ^ swz;
    v0[s] = *(const sfrag*)(Vl + rb + col);
    v1[s] = *(const sfrag*)(Vl + rb + col + 4096);
  }
  pv4(pa, v0[0], v0[1], v1[0], v1[1], O0, O1, l);
  pv4(pb, v0[2], v0[3], v1[2], v1[3], O0, O1, l);
}

template<bool MASKED>
__device__ __forceinline__ void tile32_l(const u16* __restrict__ buf, int c,
                                         const sfrag* qf, int hi, int l31, int swz,
                                         f32x16& O0, f32x16& O1, float& l) {
  const char* Kl = (const char*)buf;
  const char* Vl = Kl + 8192;
  const int rb = l31 * 128;
  f32x16 S = {};
  #pragma unroll
  for (int ks = 0; ks < 4; ++ks) {
    const int col = (hi * 16 + ks * 32) ^ swz;
    const sfrag k = *(const sfrag*)(Kl + c * 4096 + rb + col);
    S = mfma32(k, qf[ks], S);
  }
  float p[16];
  #pragma unroll
  for (int r = 0; r < 16; ++r) {
    float s = S[r];
    if (MASKED) {
      int kvo = (r & 3) + 8 * (r >> 2) + 4 * hi;
      if (kvo > l31) s = -__builtin_inff();
    }
    p[r] = __builtin_amdgcn_exp2f(s);
  }
  const int colA = (c * 64 + hi * 16) ^ swz;
  const int colB = (c * 64 + 32 + hi * 16) ^ swz;
  const sfrag v0a = *(const sfrag*)(Vl + rb + colA);
  const sfrag v0b = *(const sfrag*)(Vl + rb + colB);
  const sfrag v1a = *(const sfrag*)(Vl + rb + colA + 4096);
  const sfrag v1b = *(const sfrag*)(Vl + rb + colB + 4096);
  pv4(p, v0a, v0b, v1a, v1b, O0, O1, l);
}

__global__ __launch_bounds__(256, 4) void k_attn5(const u16* __restrict__ Qb,
                                                  const u16* __restrict__ Kb,
                                                  const u16* __restrict__ Vt,
                                                  u16* __restrict__ attOut) {
  __shared__ u16 lds[2][8192];
  const int bid = blockIdx.x;
  const int qb = 63 - (bid >> 4);
  const int bg = bid & 15;
  const int b = bg >> 3, g = bg & 7;
  const int wave = threadIdx.x >> 6, lane = threadIdx.x & 63;
  const int h = g * 4 + wave;
  const int hi = lane >> 5, l31 = lane & 31;
  const int qrow0 = qb * 32;
  const int swz = (l31 & 7) << 4;

  const u16* Qp = Qb + (((size_t)b * 32 + h) * 2048 + qrow0 + l31) * 64 + hi * 8;
  sfrag qf[4];
  #pragma unroll
  for (int ks = 0; ks < 4; ++ks) qf[ks] = *(const sfrag*)(Qp + ks * 16);

  const char* Kg = (const char*)(Kb + ((size_t)b * 8 + g) * (2048 * 64));
  const char* Vg = (const char*)(Vt + ((size_t)b * 8 + g) * (64 * 2048));

  auto stage = [&](int bufi, int t) {
    const char* Ktile = Kg + (size_t)t * 8192;
    const char* Vtile = Vg + t * 128;
    #pragma unroll
    for (int rd = 0; rd < 2; ++rd) {
      const int p = rd * 4096 + threadIdx.x * 16;
      const int d = p >> 7;
      const int cb = (p & 127) ^ ((d & 7) << 4);
      const int lbase = rd * 4096 + wave * 1024;
      gll16(Ktile + d * 128 + cb, (char*)&lds[bufi][0] + lbase);
      gll16(Vtile + (size_t)d * 4096 + cb, (char*)&lds[bufi][0] + 8192 + lbase);
    }
  };

  f32x16 O0 = {}, O1 = {};
  float lsum = 0.f;
  const int nfull = qrow0 >> 6;
  int cur = 0;
  stage(0, 0);
  for (int t = 0; t < nfull; ++t) {
    __syncthreads();
    stage(cur ^ 1, t + 1);
    tile64_l(lds[cur], qf, hi, l31, swz, O0, O1, lsum);
    cur ^= 1;
  }
  __syncthreads();
  if (qb & 1) {
    tile32_l<false>(lds[cur], 0, qf, hi, l31, swz, O0, O1, lsum);
    tile32_l<true>(lds[cur], 1, qf, hi, l31, swz, O0, O1, lsum);
  } else {
    tile32_l<true>(lds[cur], 0, qf, hi, l31, swz, O0, O1, lsum);
  }

  const float ltot = lsum + __shfl_xor(lsum, 32);
  const float inv = 1.0f / ltot;
  const size_t orow = ((size_t)b * 2048 + qrow0 + l31) * 2048 + h * 64;
  #pragma unroll
  for (int dt = 0; dt < 2; ++dt) {
    const f32x16& O = dt ? O1 : O0;
    #pragma unroll
    for (int k = 0; k < 4; ++k) {
      ushort4 o;
      o.x = f2b(O[4 * k + 0] * inv);
      o.y = f2b(O[4 * k + 1] * inv);
      o.z = f2b(O[4 * k + 2] * inv);
      o.w = f2b(O[4 * k + 3] * inv);
      *(ushort4*)&attOut[orow + dt * 32 + 8 * k + 4 * hi] = o;
    }
  }
}

extern "C" void kernel_launch(void* const* d_in, const int* in_sizes, int n_in,
                              void* d_out, int out_size, void* d_ws, size_t ws_size,
                              hipStream_t stream) {
  const float* x  = (const float*)d_in[0];
  const float* Wq = (const float*)d_in[1];
  const float* Wk = (const float*)d_in[2];
  const float* Wv = (const float*)d_in[3];
  const float* Wo = (const float*)d_in[4];
  const int* sp   = (const int*)d_in[5];
  float* y    = (float*)d_out;            // (B,T,2048) f32
  float* Kout = y + 8388608;              // (B,G,T,64) f32
  float* Vout = y + 10485760;             // (B,G,T,64) f32

  char* ws = (char*)d_ws;
  u16*    xb     = (u16*)(ws + 0);          // 16 MiB (reused as attOut later)
  u16*    Wqkvt  = (u16*)(ws + 16777216);   // 12 MiB  (3072 x 2048 bf16, transposed)
  u16*    Wot    = (u16*)(ws + 29360128);   // 8 MiB
  float2* csn    = (float2*)(ws + 37748736);// 512 KiB (2048 x 32 cos/sin)
  u16*    Qbuf   = (u16*)(ws + 88080384);   // 16 MiB  (B,H,T,hd) bf16, pre-scaled
  u16*    Kbuf   = (u16*)(ws + 104857600);  // 4 MiB   (B,G,T,hd) bf16
  u16*    Vt     = (u16*)(ws + 109051904);  // 4 MiB   (B,G,hd,T) bf16
  u16*    attOut = xb;                      // alias: xb dead after QKV GEMM

  k_convx<<<8448, 256, 0, stream>>>(x, xb, sp, csn);
  k_convTall<<<dim3(80, 32), 256, 0, stream>>>(Wq, Wk, Wv, Wo, Wqkvt, Wot);
  k_gemm128<1><<<768, 256, 0, stream>>>(xb, Wqkvt, nullptr, 3072, 2048, 32,
                                        csn, Qbuf, Kbuf, Kout, Vout);
  k_vtrans<<<dim3(32, 16), 256, 0, stream>>>(Vout, Vt);
  k_attn5<<<1024, 256, 0, stream>>>(Qbuf, Kbuf, Vt, attOut);
  k_gemm128<0><<<512, 256, 0, stream>>>(attOut, Wot, y, 2048, 2048, 32,
                                        nullptr, nullptr, nullptr, nullptr, nullptr);
}

// Round 12
// 184.248 us; speedup vs baseline: 1.1867x; 1.0038x over previous
//
#include <hip/hip_runtime.h>
#include <hip/hip_bf16.h>
#include <stdint.h>

// GQA attention block, MI355X gfx950.
// R1-R4: attention ladder (swapped-QK^T, in-reg softmax, LDS-staged K/V, swizzle).
// R5-R7: GEMM schedule experiments (256^2/8-phase null); RoPE fused into QKV GEMM.
// R8: GEMM -> m97 128x128 shape, 3 blocks/CU.
// R9: vectorized merged transposes; LDS-bounce Q/K epilogue. (184.9 us, PASS)
// R10: 512-thread attn FAILED (absmax 0.748) -> reverted; bug isolated to 8-wave
//      staging mechanics, math verified identical.
// R11: attn5 shell (256 thr, 4 waves, proven stage/barriers) but 64 q-rows/wave:
//      two Q-frag + two O/l sets per wave, tile64_l called twice per staged tile.
//      K/V traffic + barriers per q-row halved with ZERO new sync structure.

typedef __attribute__((ext_vector_type(4))) float f32x4;
typedef __attribute__((ext_vector_type(16))) float f32x16;
typedef __attribute__((ext_vector_type(8))) short sfrag;   // 8 bf16 bits
typedef __attribute__((ext_vector_type(8))) __bf16 bfrag;
typedef __attribute__((ext_vector_type(4))) unsigned int u32x4;
typedef unsigned short u16;

__device__ __forceinline__ f32x4 mfma16(sfrag a, sfrag b, f32x4 c) {
  return __builtin_amdgcn_mfma_f32_16x16x32_bf16(
      __builtin_bit_cast(bfrag, a), __builtin_bit_cast(bfrag, b), c, 0, 0, 0);
}
__device__ __forceinline__ f32x16 mfma32(sfrag a, sfrag b, f32x16 c) {
  return __builtin_amdgcn_mfma_f32_32x32x16_bf16(
      __builtin_bit_cast(bfrag, a), __builtin_bit_cast(bfrag, b), c, 0, 0, 0);
}
__device__ __forceinline__ u16 f2b(float f) {
  return __builtin_bit_cast(u16, (__bf16)f);
}
__device__ __forceinline__ unsigned pack2(float a, float b) {
  return (unsigned)f2b(a) | ((unsigned)f2b(b) << 16);
}
// a' = [a(0:31)|b(0:31)], b' = [a(32:63)|b(32:63)]
__device__ __forceinline__ void swap32(unsigned& a, unsigned& b) {
  asm("v_permlane32_swap_b32 %0, %1" : "+v"(a), "+v"(b));
}

#define GAS __attribute__((address_space(1)))
#define LAS __attribute__((address_space(3)))
__device__ __forceinline__ void gll16(const void* g, void* l) {
  __builtin_amdgcn_global_load_lds((GAS unsigned int*)g, (LAS unsigned int*)l, 16, 0, 0);
}

// ---------- x f32 -> bf16 (blocks 0..8191) + cos/sin table (blocks 8192..8447) ----------
__global__ __launch_bounds__(256) void k_convx(const float* __restrict__ X,
                                               u16* __restrict__ Y,
                                               const int* __restrict__ sp,
                                               float2* __restrict__ csn) {
  const int bid = blockIdx.x;
  if (bid < 8192) {
    const int i = (bid * 256 + threadIdx.x) * 4;
    float4 v = *(const float4*)(X + i);
    *(ushort4*)(Y + i) = make_ushort4(f2b(v.x), f2b(v.y), f2b(v.z), f2b(v.w));
  } else {
    const int i = (bid - 8192) * 256 + threadIdx.x;   // 65536 = 2048 x 32
    const int t = i >> 5, j = i & 31;
    const float freq = powf(10000.0f, -(float)j * (1.0f / 32.0f));
    const float ang = (float)(sp[0] + t) * freq;
    csn[i] = make_float2(cosf(ang), sinf(ang));
  }
}

// ---------- all weight transposes, vectorized: float4 reads, ushort4 writes ----------
__global__ __launch_bounds__(256) void k_convTall(const float* __restrict__ Wq,
                                                  const float* __restrict__ Wk,
                                                  const float* __restrict__ Wv,
                                                  const float* __restrict__ Wo,
                                                  u16* __restrict__ Wqkvt,
                                                  u16* __restrict__ Wot) {
  __shared__ float tile[64][65];
  const int bx = blockIdx.x;
  const int k0 = blockIdx.y * 64;
  const float* W; int N, n0; u16* Dst; int nd;
  if (bx < 32)      { W = Wq; N = 2048; n0 = bx * 64;        Dst = Wqkvt; nd = n0; }
  else if (bx < 40) { W = Wk; N = 512;  n0 = (bx - 32) * 64; Dst = Wqkvt; nd = 2048 + n0; }
  else if (bx < 48) { W = Wv; N = 512;  n0 = (bx - 40) * 64; Dst = Wqkvt; nd = 2560 + n0; }
  else              { W = Wo; N = 2048; n0 = (bx - 48) * 64; Dst = Wot;   nd = n0; }
  const int tid = threadIdx.x;
  #pragma unroll
  for (int it = 0; it < 4; ++it) {
    const int idx = it * 256 + tid;          // 0..1023
    const int kk = idx >> 4, nq = idx & 15;
    float4 v = *(const float4*)(W + (size_t)(k0 + kk) * N + n0 + nq * 4);
    tile[kk][nq * 4 + 0] = v.x;
    tile[kk][nq * 4 + 1] = v.y;
    tile[kk][nq * 4 + 2] = v.z;
    tile[kk][nq * 4 + 3] = v.w;
  }
  __syncthreads();
  #pragma unroll
  for (int it = 0; it < 4; ++it) {
    const int idx = it * 256 + tid;
    const int nn = idx >> 4, kq = idx & 15;
    ushort4 o;
    o.x = f2b(tile[kq * 4 + 0][nn]);
    o.y = f2b(tile[kq * 4 + 1][nn]);
    o.z = f2b(tile[kq * 4 + 2][nn]);
    o.w = f2b(tile[kq * 4 + 3][nn]);
    *(ushort4*)(Dst + (size_t)(nd + nn) * 2048 + k0 + kq * 4) = o;
  }
}

// ---------- GEMM 128x128/BK=64, 4 waves, single-buffer m97 structure ----------
// C(MxN f32) = A(MxK bf16) * Bt(NxK bf16)^T.  Grid 1D, XCD-chunked (nwg%8==0).
// LDS 32KB: A [128 rows][128B] at 0, B at 16384; XOR swizzle byte ^= ((row&7)<<4)
// on BOTH stage-source and frag-read.  MODE 0: plain C write (out-proj).
// MODE 1 (QKV): fused RoPE; wave's 64 cols = head bx*2+wn; Q/K bf16 via LDS
// bounce -> coalesced row stores; Kout/Vout f32 direct.
template<int MODE>
__global__ __launch_bounds__(256, 3) void k_gemm128(const u16* __restrict__ A,
                                                    const u16* __restrict__ Bt,
                                                    float* __restrict__ C,
                                                    int N, int K, int GY,
                                                    const float2* __restrict__ csn,
                                                    u16* __restrict__ Qb,
                                                    u16* __restrict__ Kb,
                                                    float* __restrict__ Kout,
                                                    float* __restrict__ Vout) {
  __shared__ u16 lds[16384];                    // 32 KB
  char* const L = (char*)&lds[0];
  const int tid = threadIdx.x;
  const int q8 = gridDim.x >> 3;                // nwg % 8 == 0 (bijective)
  const int id2 = (blockIdx.x & 7) * q8 + (blockIdx.x >> 3);
  const int by = id2 % GY, bx = id2 / GY;
  const int wid = tid >> 6, lane = tid & 63;
  const int wm = wid >> 1, wn = wid & 1;        // 2 x 2 waves, 64x64 C each
  const int l16 = lane & 15, l4 = lane >> 4;
  const size_t K2 = (size_t)K * 2;
  const char* Ab = (const char*)(A + (size_t)(by * 128) * K);
  const char* Bb = (const char*)(Bt + (size_t)(bx * 128) * K);
  const int NT = K >> 6;

  auto stage = [&](const char* gb, int reg, int t) {
    #pragma unroll
    for (int ld = 0; ld < 4; ++ld) {
      const int p = ld * 4096 + tid * 16;
      const int r = p >> 7;
      const int cb = (p & 127) ^ ((r & 7) << 4);
      gll16(gb + (size_t)r * K2 + (size_t)t * 128 + cb, L + reg + p);
    }
  };

  const int swz = (l16 & 7) << 4;
  const int c0 = (l4 * 16) ^ swz;               // k-half 0
  const int c1 = (64 + l4 * 16) ^ swz;          // k-half 1
  const int aOff = (wm * 64 + l16) * 128;
  const int bOff = 16384 + (wn * 64 + l16) * 128;

  f32x4 acc[4][4];
  #pragma unroll
  for (int m = 0; m < 4; ++m)
    #pragma unroll
    for (int n = 0; n < 4; ++n) acc[m][n] = f32x4{0.f, 0.f, 0.f, 0.f};

  for (int t = 0; t < NT; ++t) {
    stage(Ab, 0, t);
    stage(Bb, 16384, t);
    __syncthreads();                            // drains vmcnt -> staged data visible
    sfrag a0[4], a1[4], b0[4], b1[4];
    #pragma unroll
    for (int m = 0; m < 4; ++m) {
      a0[m] = *(const sfrag*)(L + aOff + m * 2048 + c0);
      a1[m] = *(const sfrag*)(L + aOff + m * 2048 + c1);
    }
    #pragma unroll
    for (int n = 0; n < 4; ++n) {
      b0[n] = *(const sfrag*)(L + bOff + n * 2048 + c0);
      b1[n] = *(const sfrag*)(L + bOff + n * 2048 + c1);
    }
    #pragma unroll
    for (int m = 0; m < 4; ++m)
      #pragma unroll
      for (int n = 0; n < 4; ++n) {
        acc[m][n] = mfma16(a0[m], b0[n], acc[m][n]);
        acc[m][n] = mfma16(a1[m], b1[n], acc[m][n]);
      }
    __syncthreads();                            // protect buffer overwrite
  }

  if constexpr (MODE == 0) {
    float* Cb = C + (size_t)(by * 128 + wm * 64) * N + bx * 128 + wn * 64;
    #pragma unroll
    for (int m = 0; m < 4; ++m)
      #pragma unroll
      for (int n = 0; n < 4; ++n)
        #pragma unroll
        for (int r = 0; r < 4; ++r)
          Cb[(size_t)(m * 16 + l4 * 4 + r) * N + n * 16 + l16] = acc[m][n][r];
  } else {
    const int head = bx * 2 + wn;
    const int row0 = by * 128 + wm * 64;
    if (head < 40) {                    // Q (0..31) or K (32..39): rope + LDS bounce
      u16* Lw = (u16*)(L + wid * 8192);          // this wave's 64x64 bf16 tile
      const float QS = 0.125f * 1.44269504f;     // 1/sqrt(hd) * log2(e)
      const bool isQ = head < 32;
      #pragma unroll
      for (int m = 0; m < 4; ++m)
        #pragma unroll
        for (int r = 0; r < 4; ++r) {
          const int tl = m * 16 + l4 * 4 + r;
          const int tg = row0 + tl;
          const int b = tg >> 11, t = tg & 2047;
          #pragma unroll
          for (int n = 0; n < 2; ++n) {
            const int j = n * 16 + l16;
            const float2 cz = csn[t * 32 + j];
            const float x1 = acc[m][n][r], x2 = acc[m][n + 2][r];
            const float o1 = x1 * cz.x - x2 * cz.y;
            const float o2 = x1 * cz.y + x2 * cz.x;
            if (isQ) {
              Lw[tl * 64 + j]      = f2b(o1 * QS);
              Lw[tl * 64 + j + 32] = f2b(o2 * QS);
            } else {
              Lw[tl * 64 + j]      = f2b(o1);
              Lw[tl * 64 + j + 32] = f2b(o2);
              const int g = head - 32;
              const size_t o = (((size_t)b * 8 + g) * 2048 + t) * 64 + j;
              Kout[o] = o1;  Kout[o + 32] = o2;
            }
          }
        }
      __syncthreads();   // block-uniform here (head<40 <=> bx<20); orders LDS w->r
      u16* dst = isQ ? Qb : Kb;
      const int hh = isQ ? head : (head - 32);
      const int hstride = isQ ? 32 : 8;
      #pragma unroll
      for (int it = 0; it < 8; ++it) {
        const int tl = it * 8 + (lane >> 3);
        const int col = (lane & 7) * 8;          // u16 units, 16B chunk
        const u32x4 v = *(const u32x4*)&Lw[tl * 64 + col];
        const int tg = row0 + tl;
        const int b = tg >> 11, t = tg & 2047;
        *(u32x4*)(dst + (((size_t)b * hstride + hh) * 2048 + t) * 64 + col) = v;
      }
    } else {                            // V (40..47): plain copy-out f32
      const int g = head - 40;
      #pragma unroll
      for (int m = 0; m < 4; ++m)
        #pragma unroll
        for (int r = 0; r < 4; ++r) {
          const int tg = row0 + m * 16 + l4 * 4 + r;
          const int b = tg >> 11, t = tg & 2047;
          const size_t o = (((size_t)b * 8 + g) * 2048 + t) * 64;
          #pragma unroll
          for (int n = 0; n < 4; ++n)
            Vout[o + n * 16 + l16] = acc[m][n][r];
        }
    }
  }
}

// ---------- V transpose: Vout f32 (B,G,T,64) -> Vt bf16 (B,G,hd,T) ----------
__global__ __launch_bounds__(256) void k_vtrans(const float* __restrict__ Vout,
                                                u16* __restrict__ Vt) {
  __shared__ float tile[64][65];
  int t0 = blockIdx.x * 64;
  int bg = blockIdx.y;
  const float* src = Vout + (size_t)bg * (2048 * 64);
  #pragma unroll
  for (int p = 0; p < 16; ++p) {
    int idx = p * 256 + threadIdx.x;
    int tt = idx >> 6, d = idx & 63;
    tile[tt][d] = src[(size_t)(t0 + tt) * 64 + d];
  }
  __syncthreads();
  #pragma unroll
  for (int p = 0; p < 16; ++p) {
    int idx = p * 256 + threadIdx.x;
    int d = idx >> 6, tt = idx & 63;
    Vt[((size_t)bg * 64 + d) * 2048 + t0 + tt] = f2b(tile[tt][d]);
  }
}

// ---------- Flash attention v7: attn5 shell, 64 q-rows per wave ----------
__device__ __forceinline__ void pv4(const float* p, sfrag v0a, sfrag v0b,
                                    sfrag v1a, sfrag v1b,
                                    f32x16& O0, f32x16& O1, float& l) {
  unsigned w[8];
  #pragma unroll
  for (int j = 0; j < 8; ++j) w[j] = pack2(p[2 * j], p[2 * j + 1]);
  swap32(w[0], w[2]);
  swap32(w[1], w[3]);
  swap32(w[4], w[6]);
  swap32(w[5], w[7]);
  const sfrag pf0 = __builtin_bit_cast(sfrag, u32x4{w[0], w[1], w[2], w[3]});
  const sfrag pf1 = __builtin_bit_cast(sfrag, u32x4{w[4], w[5], w[6], w[7]});
  O0 = mfma32(v0a, pf0, O0);
  O0 = mfma32(v0b, pf1, O0);
  O1 = mfma32(v1a, pf0, O1);
  O1 = mfma32(v1b, pf1, O1);
  float s[8];
  #pragma unroll
  for (int j = 0; j < 8; ++j) s[j] = p[j] + p[j + 8];
  #pragma unroll
  for (int j = 0; j < 4; ++j) s[j] = s[j] + s[j + 4];
  l += (s[0] + s[1]) + (s[2] + s[3]);
}

__device__ __forceinline__ void tile64_l(const u16* __restrict__ buf,
                                         const sfrag* qf, int hi, int l31, int swz,
                                         f32x16& O0, f32x16& O1, float& l) {
  const char* Kl = (const char*)buf;
  const char* Vl = Kl + 8192;
  const int rb = l31 * 128;
  f32x16 Sa = {}, Sb = {};
  #pragma unroll
  for (int ks = 0; ks < 4; ++ks) {
    const int col = (hi * 16 + ks * 32) ^ swz;
    const sfrag ka = *(const sfrag*)(Kl + rb + col);
    const sfrag kb = *(const sfrag*)(Kl + rb + col + 4096);
    Sa = mfma32(ka, qf[ks], Sa);
    Sb = mfma32(kb, qf[ks], Sb);
  }
  float pa[16], pb[16];
  #pragma unroll
  for (int r = 0; r < 16; ++r) {
    pa[r] = __builtin_amdgcn_exp2f(Sa[r]);
    pb[r] = __builtin_amdgcn_exp2f(Sb[r]);
  }
  sfrag v0[4], v1[4];
  #pragma unroll
  for (int s = 0; s < 4; ++s) {
    const int col = (s * 32 + hi * 16) ^ swz;
    v0[s] = *(const sfrag*)(Vl + rb + col);
    v1[s] = *(const sfrag*)(Vl + rb + col + 4096);
  }
  pv4(pa, v0[0], v0[1], v1[0], v1[1], O0, O1, l);
  pv4(pb, v0[2], v0[3], v1[2], v1[3], O0, O1, l);
}

template<bool MASKED>
__device__ __forceinline__ void tile32_l(const u16* __restrict__ buf, int c,
                                         const sfrag* qf, int hi, int l31, int swz,
                                         f32x16& O0, f32x16& O1, float& l) {
  const char* Kl = (const char*)buf;
  const char* Vl = Kl + 8192;
  const int rb = l31 * 128;
  f32x16 S = {};
  #pragma unroll
  for (int ks = 0; ks < 4; ++ks) {
    const int col = (hi * 16 + ks * 32) ^ swz;
    const sfrag k = *(const sfrag*)(Kl + c * 4096 + rb + col);
    S = mfma32(k, qf[ks], S);
  }
  float p[16];
  #pragma unroll
  for (int r = 0; r < 16; ++r) {
    float s = S[r];
    if (MASKED) {
      int kvo = (r & 3) + 8 * (r >> 2) + 4 * hi;
      if (kvo > l31) s = -__builtin_inff();
    }
    p[r] = __builtin_amdgcn_exp2f(s);
  }
  const int colA = (c * 64 + hi * 16) ^ swz;
  const int colB = (c * 64 + 32 + hi * 16) ^ swz;
  const sfrag v0a = *(const sfrag*)(Vl + rb + colA);
  const sfrag v0b = *(const sfrag*)(Vl + rb + colB);
  const sfrag v1a = *(const sfrag*)(Vl + rb + colA + 4096);
  const sfrag v1b = *(const sfrag*)(Vl + rb + colB + 4096);
  pv4(p, v0a, v0b, v1a, v1b, O0, O1, l);
}

// Block = (qb2, b, g): 4 waves = 4 heads; each wave owns 64 q-rows (two subtiles).
// Stage/barrier skeleton identical to the R9-proven k_attn5. 512 blocks.
__global__ __launch_bounds__(256, 2) void k_attn7(const u16* __restrict__ Qb,
                                                  const u16* __restrict__ Kb,
                                                  const u16* __restrict__ Vt,
                                                  u16* __restrict__ attOut) {
  __shared__ u16 lds[2][8192];
  const int bid = blockIdx.x;                 // 512 blocks
  const int qb2 = 31 - (bid >> 4);            // heavy q-blocks launch first
  const int bg = bid & 15;
  const int b = bg >> 3, g = bg & 7;
  const int wave = threadIdx.x >> 6, lane = threadIdx.x & 63;
  const int h = g * 4 + wave;
  const int hi = lane >> 5, l31 = lane & 31;
  const int qrow0 = qb2 * 64;                 // this wave: rows qrow0 .. qrow0+63
  const int swz = (l31 & 7) << 4;

  const u16* Qp0 = Qb + (((size_t)b * 32 + h) * 2048 + qrow0 + l31) * 64 + hi * 8;
  sfrag qf0[4], qf1[4];
  #pragma unroll
  for (int ks = 0; ks < 4; ++ks) {
    qf0[ks] = *(const sfrag*)(Qp0 + ks * 16);
    qf1[ks] = *(const sfrag*)(Qp0 + 32 * 64 + ks * 16);
  }

  const char* Kg = (const char*)(Kb + ((size_t)b * 8 + g) * (2048 * 64));
  const char* Vg = (const char*)(Vt + ((size_t)b * 8 + g) * (64 * 2048));

  // stage: verbatim from R9's k_attn5 (256 threads, rd-loop)
  auto stage = [&](int bufi, int t) {
    const char* Ktile = Kg + (size_t)t * 8192;
    const char* Vtile = Vg + t * 128;
    #pragma unroll
    for (int rd = 0; rd < 2; ++rd) {
      const int p = rd * 4096 + threadIdx.x * 16;
      const int d = p >> 7;
      const int cb = (p & 127) ^ ((d & 7) << 4);
      const int lbase = rd * 4096 + wave * 1024;
      gll16(Ktile + d * 128 + cb, (char*)&lds[bufi][0] + lbase);
      gll16(Vtile + (size_t)d * 4096 + cb, (char*)&lds[bufi][0] + 8192 + lbase);
    }
  };

  f32x16 O00 = {}, O01 = {}, O10 = {}, O11 = {};
  float ls0 = 0.f, ls1 = 0.f;
  const int nfull = qb2;          // full 64-kv tiles for BOTH subtiles
  int cur = 0;
  stage(0, 0);
  for (int t = 0; t < nfull; ++t) {
    __syncthreads();              // vmcnt drained -> lds[cur] ready
    stage(cur ^ 1, t + 1);        // prefetch next tile (tail exists at t=nfull)
    tile64_l(lds[cur], qf0, hi, l31, swz, O00, O01, ls0);
    tile64_l(lds[cur], qf1, hi, l31, swz, O10, O11, ls1);
    cur ^= 1;
  }
  __syncthreads();                // tail tile (index qb2): kv [qb2*64, qb2*64+64)
  tile32_l<true >(lds[cur], 0, qf0, hi, l31, swz, O00, O01, ls0);  // sub0 diagonal
  tile32_l<false>(lds[cur], 0, qf1, hi, l31, swz, O10, O11, ls1);  // sub1 full half
  tile32_l<true >(lds[cur], 1, qf1, hi, l31, swz, O10, O11, ls1);  // sub1 diagonal

  #pragma unroll
  for (int sb = 0; sb < 2; ++sb) {
    const float lsum = sb ? ls1 : ls0;
    const float ltot = lsum + __shfl_xor(lsum, 32);
    const float inv = 1.0f / ltot;
    const size_t orow = ((size_t)b * 2048 + qrow0 + sb * 32 + l31) * 2048 + h * 64;
    #pragma unroll
    for (int dt = 0; dt < 2; ++dt) {
      const f32x16& O = sb ? (dt ? O11 : O10) : (dt ? O01 : O00);
      #pragma unroll
      for (int k = 0; k < 4; ++k) {
        ushort4 o;
        o.x = f2b(O[4 * k + 0] * inv);
        o.y = f2b(O[4 * k + 1] * inv);
        o.z = f2b(O[4 * k + 2] * inv);
        o.w = f2b(O[4 * k + 3] * inv);
        *(ushort4*)&attOut[orow + dt * 32 + 8 * k + 4 * hi] = o;
      }
    }
  }
}

extern "C" void kernel_launch(void* const* d_in, const int* in_sizes, int n_in,
                              void* d_out, int out_size, void* d_ws, size_t ws_size,
                              hipStream_t stream) {
  const float* x  = (const float*)d_in[0];
  const float* Wq = (const float*)d_in[1];
  const float* Wk = (const float*)d_in[2];
  const float* Wv = (const float*)d_in[3];
  const float* Wo = (const float*)d_in[4];
  const int* sp   = (const int*)d_in[5];
  float* y    = (float*)d_out;            // (B,T,2048) f32
  float* Kout = y + 8388608;              // (B,G,T,64) f32
  float* Vout = y + 10485760;             // (B,G,T,64) f32

  char* ws = (char*)d_ws;
  u16*    xb     = (u16*)(ws + 0);          // 16 MiB (reused as attOut later)
  u16*    Wqkvt  = (u16*)(ws + 16777216);   // 12 MiB  (3072 x 2048 bf16, transposed)
  u16*    Wot    = (u16*)(ws + 29360128);   // 8 MiB
  float2* csn    = (float2*)(ws + 37748736);// 512 KiB (2048 x 32 cos/sin)
  u16*    Qbuf   = (u16*)(ws + 88080384);   // 16 MiB  (B,H,T,hd) bf16, pre-scaled
  u16*    Kbuf   = (u16*)(ws + 104857600);  // 4 MiB   (B,G,T,hd) bf16
  u16*    Vt     = (u16*)(ws + 109051904);  // 4 MiB   (B,G,hd,T) bf16
  u16*    attOut = xb;                      // alias: xb dead after QKV GEMM

  k_convx<<<8448, 256, 0, stream>>>(x, xb, sp, csn);
  k_convTall<<<dim3(80, 32), 256, 0, stream>>>(Wq, Wk, Wv, Wo, Wqkvt, Wot);
  k_gemm128<1><<<768, 256, 0, stream>>>(xb, Wqkvt, nullptr, 3072, 2048, 32,
                                        csn, Qbuf, Kbuf, Kout, Vout);
  k_vtrans<<<dim3(32, 16), 256, 0, stream>>>(Vout, Vt);
  k_attn7<<<512, 256, 0, stream>>>(Qbuf, Kbuf, Vt, attOut);
  k_gemm128<0><<<512, 256, 0, stream>>>(attOut, Wot, y, 2048, 2048, 32,
                                        nullptr, nullptr, nullptr, nullptr, nullptr);
}